// Round 14
// baseline (158.500 us; speedup 1.0000x reference)
//
#include <hip/hip_runtime.h>
#include <math.h>

#define NUM_NODES 2048
#define BATCH 2
#define NHEAD 8
#define SEQ 168
#define HID 256
#define DHEAD 32
#define UPART 80
#define UTOP 40
#define L0C 81
#define L1C 39
#define L2C 19
#define C0 8
#define C1 16
#define C2 32
#define FCIN 608   // 32*19
#define ROWS 4096  // BATCH*NUM_NODES

// ---------------- Kernel 0: transpose the three weight matrices ----------------
__global__ __launch_bounds__(256) void transpose3_kernel(
    const float* __restrict__ fc_w, const float* __restrict__ q_w, const float* __restrict__ k_w,
    float* __restrict__ fc_wT, float* __restrict__ q_wT, float* __restrict__ k_wT)
{
    __shared__ float t[32][33];
    const int z = blockIdx.z;
    const float* in = (z == 0) ? fc_w : ((z == 1) ? q_w : k_w);
    float* out      = (z == 0) ? fc_wT : ((z == 1) ? q_wT : k_wT);
    const int M = 256;
    const int N = (z == 0) ? FCIN : HID;
    const int bx = blockIdx.x * 32;
    const int by = blockIdx.y * 32;
    if (bx >= N) return;
    const int tx = threadIdx.x & 31, ty0 = threadIdx.x >> 5;
    for (int i = ty0; i < 32; i += 8) {
        int r = by + i, c = bx + tx;
        if (r < M && c < N) t[i][tx] = in[(size_t)r * N + c];
    }
    __syncthreads();
    for (int i = ty0; i < 32; i += 8) {
        int r = bx + i, c = by + tx;
        if (r < N && c < M) out[(size_t)r * M + c] = t[tx][i];
    }
}

// ---------------- Kernel 1: conv chain, ONE WAVE PER ROW (no barriers) ----------------
#define XS_OFF 0
#define H0_OFF 168            // 8 ch x stride 82 = 656
#define H0_STR 82
#define H1_OFF (168+656)      // 16 ch x stride 40 = 640
#define H1_STR 40
#define H2_OFF (168+656+640)  // 32 ch x stride 20 = 640
#define H2_STR 20
#define WAVE_LDS 2112
__global__ __launch_bounds__(256) void conv_chain_kernel(
    const float* __restrict__ x,
    const float* __restrict__ w0, const float* __restrict__ b0,
    const float* __restrict__ w1, const float* __restrict__ b1,
    const float* __restrict__ w2, const float* __restrict__ b2,
    const float* __restrict__ g0, const float* __restrict__ be0,
    const float* __restrict__ g1, const float* __restrict__ be1,
    const float* __restrict__ g2, const float* __restrict__ be2,
    float* __restrict__ Hout)
{
    __shared__ float lds[4][WAVE_LDS];
    const int tid  = threadIdx.x;
    const int lane = tid & 63;
    const int wave = tid >> 6;
    const int row  = blockIdx.x * 4 + wave;
    float* W = lds[wave];

    {
        const float4* xp = (const float4*)(x + (size_t)row * SEQ);
        if (lane < SEQ/4) *(float4*)&W[XS_OFF + lane*4] = xp[lane];
    }

    // ---- conv0 (1->8, k=7, s=2) + relu ----
    {
        const int c = lane >> 3, sub = lane & 7;
        float wr[7];
        #pragma unroll
        for (int j = 0; j < 7; ++j) wr[j] = w0[c*7 + j];
        const float bias = b0[c];
        for (int t = sub; t < L0C; t += 8) {
            const float* xp = &W[XS_OFF + 2*t];
            float2 a = *(const float2*)(xp);
            float2 b = *(const float2*)(xp+2);
            float2 d = *(const float2*)(xp+4);
            float  e = xp[6];
            float acc = bias + wr[0]*a.x + wr[1]*a.y + wr[2]*b.x + wr[3]*b.y
                             + wr[4]*d.x + wr[5]*d.y + wr[6]*e;
            W[H0_OFF + c*H0_STR + t] = fmaxf(acc, 0.f);
        }
    }
    // ---- LN0 ----
    {
        const int c = lane >> 3, sub = lane & 7;
        float s = 0.f, s2 = 0.f;
        for (int t = sub; t < L0C; t += 8) { float v = W[H0_OFF + c*H0_STR + t]; s += v; s2 += v*v; }
        #pragma unroll
        for (int m = 4; m >= 1; m >>= 1) { s += __shfl_xor(s, m); s2 += __shfl_xor(s2, m); }
        float mean = s / (float)L0C;
        float inv  = rsqrtf(s2 / (float)L0C - mean*mean + 1e-5f);
        for (int t = sub; t < L0C; t += 8)
            W[H0_OFF + c*H0_STR + t] = (W[H0_OFF + c*H0_STR + t] - mean) * inv * g0[t] + be0[t];
    }
    // ---- conv1 (8->16, k=5, s=2) + relu ----
    {
        const int c = lane >> 2, sub = lane & 3;
        float wr[40];
        {
            const float4* wp = (const float4*)(w1 + c*40);
            #pragma unroll
            for (int j4 = 0; j4 < 10; ++j4) {
                float4 v = wp[j4];
                wr[j4*4+0] = v.x; wr[j4*4+1] = v.y; wr[j4*4+2] = v.z; wr[j4*4+3] = v.w;
            }
        }
        const float bias = b1[c];
        for (int t = sub; t < L1C; t += 4) {
            float acc = bias;
            #pragma unroll
            for (int ci = 0; ci < C0; ++ci) {
                const float* hp = &W[H0_OFF + ci*H0_STR + 2*t];
                float2 a = *(const float2*)(hp);
                float2 b = *(const float2*)(hp+2);
                float  e = hp[4];
                acc += wr[ci*5+0]*a.x + wr[ci*5+1]*a.y + wr[ci*5+2]*b.x
                     + wr[ci*5+3]*b.y + wr[ci*5+4]*e;
            }
            W[H1_OFF + c*H1_STR + t] = fmaxf(acc, 0.f);
        }
    }
    // ---- LN1 ----
    {
        const int c = lane >> 2, sub = lane & 3;
        float s = 0.f, s2 = 0.f;
        for (int t = sub; t < L1C; t += 4) { float v = W[H1_OFF + c*H1_STR + t]; s += v; s2 += v*v; }
        #pragma unroll
        for (int m = 2; m >= 1; m >>= 1) { s += __shfl_xor(s, m); s2 += __shfl_xor(s2, m); }
        float mean = s / (float)L1C;
        float inv  = rsqrtf(s2 / (float)L1C - mean*mean + 1e-5f);
        for (int t = sub; t < L1C; t += 4)
            W[H1_OFF + c*H1_STR + t] = (W[H1_OFF + c*H1_STR + t] - mean) * inv * g1[t] + be1[t];
    }
    // ---- conv2 (16->32, k=3, s=2) + relu ----
    {
        const int c = lane >> 1, sub = lane & 1;
        float wr[48];
        {
            const float4* wp = (const float4*)(w2 + c*48);
            #pragma unroll
            for (int j4 = 0; j4 < 12; ++j4) {
                float4 v = wp[j4];
                wr[j4*4+0] = v.x; wr[j4*4+1] = v.y; wr[j4*4+2] = v.z; wr[j4*4+3] = v.w;
            }
        }
        const float bias = b2[c];
        for (int t = sub; t < L2C; t += 2) {
            float acc = bias;
            #pragma unroll
            for (int ci = 0; ci < C1; ++ci) {
                const float* hp = &W[H1_OFF + ci*H1_STR + 2*t];
                float2 a = *(const float2*)(hp);
                float  e = hp[2];
                acc += wr[ci*3+0]*a.x + wr[ci*3+1]*a.y + wr[ci*3+2]*e;
            }
            W[H2_OFF + c*H2_STR + t] = fmaxf(acc, 0.f);
        }
    }
    // ---- LN2 ----
    {
        const int c = lane >> 1, sub = lane & 1;
        float s = 0.f, s2 = 0.f;
        for (int t = sub; t < L2C; t += 2) { float v = W[H2_OFF + c*H2_STR + t]; s += v; s2 += v*v; }
        s += __shfl_xor(s, 1); s2 += __shfl_xor(s2, 1);
        float mean = s / (float)L2C;
        float inv  = rsqrtf(s2 / (float)L2C - mean*mean + 1e-5f);
        for (int t = sub; t < L2C; t += 2)
            W[H2_OFF + c*H2_STR + t] = (W[H2_OFF + c*H2_STR + t] - mean) * inv * g2[t] + be2[t];
    }
    for (int i = lane; i < FCIN; i += 64) {
        int c = i / L2C, t = i - c*L2C;
        Hout[(size_t)row*FCIN + i] = W[H2_OFF + c*H2_STR + t];
    }
}

// ---------------- Kernel 2: fc+relu+LN3 + q,k projections ----------------
// R13 structure + explicit register double-buffer on the weight stream:
// k-step 8, prefetch next iteration's 8 float2 weights before the FMA block
// so their ~200cy latency is covered by the current 512 FMA-cycles.
__global__ __launch_bounds__(512) void fc_qk_kernel(
    const float* __restrict__ Hin,
    const float* __restrict__ fc_wT, const float* __restrict__ fc_b,
    const float* __restrict__ g3, const float* __restrict__ be3,
    const float* __restrict__ q_wT, const float* __restrict__ q_b,
    const float* __restrict__ k_wT, const float* __restrict__ k_b,
    float* __restrict__ q_out, float* __restrict__ k_out)
{
    __shared__ float Hlds[8][FCIN];     // 19.4KB: staged H rows 0..7
    __shared__ float part[3][16][HID];  // 48KB: partials from kh=1..3
    __shared__ float hm[16][HID];       // 16KB: activations

    const int tid  = threadIdx.x;
    const int lane = tid & 63;
    const int wave = tid >> 6;
    const int cg   = __builtin_amdgcn_readfirstlane(wave & 1);   // col group 0/1
    const int kh   = __builtin_amdgcn_readfirstlane(wave >> 1);  // k quarter 0..3
    const int c0   = cg * 128 + lane * 2;                        // 2 contiguous cols
    const int r0   = blockIdx.x * 16;

    // ---------- stage H rows 0..7 (contiguous 19.4KB) ----------
    {
        const float4* src = (const float4*)(Hin + (size_t)r0 * FCIN);
        float4* dst = (float4*)&Hlds[0][0];
        for (int i4 = tid; i4 < 8*FCIN/4; i4 += 512) dst[i4] = src[i4];
    }
    __syncthreads();   // S0

    float2 acc[16];

    // ---------- fc partial over this wave's k-quarter (dbuf weights) ----------
    #pragma unroll
    for (int r = 0; r < 16; ++r) acc[r] = make_float2(0.f, 0.f);
    {
        const int kbeg = kh * (FCIN/4), kend = kbeg + FCIN/4;   // 152 ks, 19 iters of 8
        const float* Hg = Hin + (size_t)(r0 + 8) * FCIN;        // rows 8..15, uniform base
        float2 wb[8];
        #pragma unroll
        for (int j = 0; j < 8; ++j)
            wb[j] = *(const float2*)(fc_wT + (size_t)(kbeg + j)*HID + c0);
        for (int k = kbeg; k < kend; k += 8) {
            float2 wn[8];
            const int kn = k + 8;
            if (kn < kend) {
                #pragma unroll
                for (int j = 0; j < 8; ++j)
                    wn[j] = *(const float2*)(fc_wT + (size_t)(kn + j)*HID + c0);
            }
            #pragma unroll
            for (int kk = 0; kk < 8; kk += 4) {
                #pragma unroll
                for (int r = 0; r < 8; ++r) {
                    float4 h4 = *(const float4*)&Hlds[r][k + kk];
                    acc[r].x += h4.x*wb[kk].x + h4.y*wb[kk+1].x + h4.z*wb[kk+2].x + h4.w*wb[kk+3].x;
                    acc[r].y += h4.x*wb[kk].y + h4.y*wb[kk+1].y + h4.z*wb[kk+2].y + h4.w*wb[kk+3].y;
                }
                #pragma unroll
                for (int r = 0; r < 8; ++r) {
                    float4 h4 = *(const float4*)(Hg + (size_t)r*FCIN + k + kk);   // uniform addr
                    acc[8+r].x += h4.x*wb[kk].x + h4.y*wb[kk+1].x + h4.z*wb[kk+2].x + h4.w*wb[kk+3].x;
                    acc[8+r].y += h4.x*wb[kk].y + h4.y*wb[kk+1].y + h4.z*wb[kk+2].y + h4.w*wb[kk+3].y;
                }
            }
            if (kn < kend) {
                #pragma unroll
                for (int j = 0; j < 8; ++j) wb[j] = wn[j];
            }
        }
    }
    if (kh != 0) {
        #pragma unroll
        for (int r = 0; r < 16; ++r) *(float2*)&part[kh-1][r][c0] = acc[r];
    }
    __syncthreads();   // S1

    // ---------- reduce + bias + relu -> hm (kh==0 waves) ----------
    if (kh == 0) {
        float2 b2v = *(const float2*)(fc_b + c0);
        #pragma unroll
        for (int r = 0; r < 16; ++r) {
            float2 p0 = *(const float2*)&part[0][r][c0];
            float2 p1 = *(const float2*)&part[1][r][c0];
            float2 p2 = *(const float2*)&part[2][r][c0];
            float2 e;
            e.x = fmaxf(acc[r].x + p0.x + p1.x + p2.x + b2v.x, 0.f);
            e.y = fmaxf(acc[r].y + p0.y + p1.y + p2.y + b2v.y, 0.f);
            *(float2*)&hm[r][c0] = e;
        }
    }
    __syncthreads();   // S2

    // ---------- LN3: wave handles rows 2*wave, 2*wave+1 ----------
    {
        float4 gg = *(const float4*)(g3 + lane*4);
        float4 bb = *(const float4*)(be3 + lane*4);
        #pragma unroll
        for (int rr = 0; rr < 2; ++rr) {
            const int row = wave*2 + rr;
            float4 v = *(const float4*)&hm[row][lane*4];
            float s  = v.x + v.y + v.z + v.w;
            float s2 = v.x*v.x + v.y*v.y + v.z*v.z + v.w*v.w;
            #pragma unroll
            for (int m = 32; m >= 1; m >>= 1) { s += __shfl_xor(s, m); s2 += __shfl_xor(s2, m); }
            float mean = s * (1.f/256.f);
            float inv  = rsqrtf(s2 * (1.f/256.f) - mean*mean + 1e-5f);
            v.x = (v.x - mean) * inv * gg.x + bb.x;
            v.y = (v.y - mean) * inv * gg.y + bb.y;
            v.z = (v.z - mean) * inv * gg.z + bb.z;
            v.w = (v.w - mean) * inv * gg.w + bb.w;
            *(float4*)&hm[row][lane*4] = v;
        }
    }
    __syncthreads();   // S3

    // ---------- q projection (dbuf weights) ----------
    #pragma unroll
    for (int r = 0; r < 16; ++r) acc[r] = make_float2(0.f, 0.f);
    {
        const int kbeg = kh * (HID/4), kend = kbeg + HID/4;   // 64 ks, 8 iters of 8
        float2 wb[8];
        #pragma unroll
        for (int j = 0; j < 8; ++j)
            wb[j] = *(const float2*)(q_wT + (size_t)(kbeg + j)*HID + c0);
        for (int k = kbeg; k < kend; k += 8) {
            float2 wn[8];
            const int kn = k + 8;
            if (kn < kend) {
                #pragma unroll
                for (int j = 0; j < 8; ++j)
                    wn[j] = *(const float2*)(q_wT + (size_t)(kn + j)*HID + c0);
            }
            #pragma unroll
            for (int kk = 0; kk < 8; kk += 4) {
                #pragma unroll
                for (int r = 0; r < 16; ++r) {
                    float4 h4 = *(const float4*)&hm[r][k + kk];
                    acc[r].x += h4.x*wb[kk].x + h4.y*wb[kk+1].x + h4.z*wb[kk+2].x + h4.w*wb[kk+3].x;
                    acc[r].y += h4.x*wb[kk].y + h4.y*wb[kk+1].y + h4.z*wb[kk+2].y + h4.w*wb[kk+3].y;
                }
            }
            if (kn < kend) {
                #pragma unroll
                for (int j = 0; j < 8; ++j) wb[j] = wn[j];
            }
        }
    }
    if (kh != 0) {
        #pragma unroll
        for (int r = 0; r < 16; ++r) *(float2*)&part[kh-1][r][c0] = acc[r];
    }
    __syncthreads();   // S4
    if (kh == 0) {
        float2 b2v = *(const float2*)(q_b + c0);
        #pragma unroll
        for (int r = 0; r < 16; ++r) {
            float2 p0 = *(const float2*)&part[0][r][c0];
            float2 p1 = *(const float2*)&part[1][r][c0];
            float2 p2 = *(const float2*)&part[2][r][c0];
            float2 o;
            o.x = acc[r].x + p0.x + p1.x + p2.x + b2v.x;
            o.y = acc[r].y + p0.y + p1.y + p2.y + b2v.y;
            *(float2*)(q_out + (size_t)(r0 + r)*HID + c0) = o;
        }
    }

    // ---------- k projection (dbuf weights; compute first, barrier, part rewrite) ----------
    #pragma unroll
    for (int r = 0; r < 16; ++r) acc[r] = make_float2(0.f, 0.f);
    {
        const int kbeg = kh * (HID/4), kend = kbeg + HID/4;
        float2 wb[8];
        #pragma unroll
        for (int j = 0; j < 8; ++j)
            wb[j] = *(const float2*)(k_wT + (size_t)(kbeg + j)*HID + c0);
        for (int k = kbeg; k < kend; k += 8) {
            float2 wn[8];
            const int kn = k + 8;
            if (kn < kend) {
                #pragma unroll
                for (int j = 0; j < 8; ++j)
                    wn[j] = *(const float2*)(k_wT + (size_t)(kn + j)*HID + c0);
            }
            #pragma unroll
            for (int kk = 0; kk < 8; kk += 4) {
                #pragma unroll
                for (int r = 0; r < 16; ++r) {
                    float4 h4 = *(const float4*)&hm[r][k + kk];
                    acc[r].x += h4.x*wb[kk].x + h4.y*wb[kk+1].x + h4.z*wb[kk+2].x + h4.w*wb[kk+3].x;
                    acc[r].y += h4.x*wb[kk].y + h4.y*wb[kk+1].y + h4.z*wb[kk+2].y + h4.w*wb[kk+3].y;
                }
            }
            if (kn < kend) {
                #pragma unroll
                for (int j = 0; j < 8; ++j) wb[j] = wn[j];
            }
        }
    }
    __syncthreads();   // S5: kh0 done reading q partials
    if (kh != 0) {
        #pragma unroll
        for (int r = 0; r < 16; ++r) *(float2*)&part[kh-1][r][c0] = acc[r];
    }
    __syncthreads();   // S6
    if (kh == 0) {
        float2 b2v = *(const float2*)(k_b + c0);
        #pragma unroll
        for (int r = 0; r < 16; ++r) {
            float2 p0 = *(const float2*)&part[0][r][c0];
            float2 p1 = *(const float2*)&part[1][r][c0];
            float2 p2 = *(const float2*)&part[2][r][c0];
            float2 o;
            o.x = acc[r].x + p0.x + p1.x + p2.x + b2v.x;
            o.y = acc[r].y + p0.y + p1.y + p2.y + b2v.y;
            *(float2*)(k_out + (size_t)(r0 + r)*HID + c0) = o;
        }
    }
}

// ---------------- Kernel 3: QK_sample + M ----------------
__global__ __launch_bounds__(256) void qk_sample_kernel(
    const float* __restrict__ q, const float* __restrict__ k,
    const int* __restrict__ idx_g, float* __restrict__ M)
{
    __shared__ int sidx[UPART];
    __shared__ float qrow[HID];
    __shared__ float qk[NHEAD][UPART];
    const int bl = blockIdx.x;            // b*2048 + l
    const int b = bl >> 11, l = bl & (NUM_NODES-1);
    const int tid = threadIdx.x;
    if (tid < UPART) sidx[tid] = idx_g[l*UPART + tid];
    qrow[tid] = q[(size_t)bl*HID + tid];
    __syncthreads();
    for (int task = tid; task < NHEAD*UPART; task += 256) {
        int h = task / UPART, s = task % UPART;
        const float4* kp = (const float4*)(k + (size_t)(b*NUM_NODES + sidx[s])*HID + h*DHEAD);
        const float4* qp = (const float4*)(qrow + h*DHEAD);
        float acc = 0.f;
        #pragma unroll
        for (int d4 = 0; d4 < 8; ++d4) {
            float4 kv = kp[d4], qv = qp[d4];
            acc += qv.x*kv.x + qv.y*kv.y + qv.z*kv.z + qv.w*kv.w;
        }
        qk[h][s] = acc;
    }
    __syncthreads();
    {
        const int h = tid >> 5, sub = tid & 31;
        float mx = -INFINITY, sm = 0.f;
        for (int s = sub; s < UPART; s += 32) { float v = qk[h][s]; mx = fmaxf(mx, v); sm += v; }
        #pragma unroll
        for (int m = 16; m >= 1; m >>= 1) {
            mx = fmaxf(mx, __shfl_xor(mx, m));
            sm += __shfl_xor(sm, m);
        }
        if (sub == 0)
            M[(size_t)(b*NHEAD + h)*NUM_NODES + l] = mx - sm / (float)NUM_NODES;
    }
}

// ---------------- Kernel 4: top-40 per (b,h) via 4-round radix select ----------------
__global__ __launch_bounds__(256) void topk_kernel(
    const float* __restrict__ M, int* __restrict__ Mtop)
{
    __shared__ unsigned int keys[NUM_NODES];
    __shared__ unsigned int hist[256];
    __shared__ int tiebuf[NUM_NODES];
    __shared__ int cnt_gt, cnt_tie;
    __shared__ unsigned int s_prefix;
    __shared__ int s_r;

    const int bh = blockIdx.x;
    const int tid = threadIdx.x;

    for (int i = tid; i < NUM_NODES; i += 256) {
        unsigned int u = __float_as_uint(M[(size_t)bh*NUM_NODES + i]);
        keys[i] = (u & 0x80000000u) ? ~u : (u | 0x80000000u);
    }
    if (tid == 0) { s_prefix = 0u; s_r = UTOP; cnt_gt = 0; cnt_tie = 0; }
    __syncthreads();

    for (int shift = 24; shift >= 0; shift -= 8) {
        hist[tid] = 0u;
        __syncthreads();
        const unsigned int prefix = s_prefix;
        const unsigned int pmask = (shift == 24) ? 0u : ~((1u << (shift + 8)) - 1u);
        for (int i = tid; i < NUM_NODES; i += 256) {
            unsigned int k = keys[i];
            if ((k & pmask) == prefix)
                atomicAdd(&hist[(k >> shift) & 0xFFu], 1u);
        }
        __syncthreads();
        if (tid < 64) {
            const int b0 = 255 - tid * 4;
            unsigned int c0 = hist[b0], c1 = hist[b0-1], c2 = hist[b0-2], c3 = hist[b0-3];
            unsigned int gsum = c0 + c1 + c2 + c3;
            unsigned int pre = gsum;
            #pragma unroll
            for (int d = 1; d < 64; d <<= 1) {
                unsigned int o = __shfl_up(pre, d);
                if (tid >= d) pre += o;
            }
            pre -= gsum;
            const unsigned int r = (unsigned int)s_r;
            unsigned int ca0 = pre, ca1 = ca0 + c0, ca2 = ca1 + c1, ca3 = ca2 + c2;
            if (ca0 < r && r <= ca0 + c0) { s_prefix = prefix | ((unsigned int)(b0  ) << shift); s_r = (int)(r - ca0); }
            if (ca1 < r && r <= ca1 + c1) { s_prefix = prefix | ((unsigned int)(b0-1) << shift); s_r = (int)(r - ca1); }
            if (ca2 < r && r <= ca2 + c2) { s_prefix = prefix | ((unsigned int)(b0-2) << shift); s_r = (int)(r - ca2); }
            if (ca3 < r && r <= ca3 + c3) { s_prefix = prefix | ((unsigned int)(b0-3) << shift); s_r = (int)(r - ca3); }
        }
        __syncthreads();
    }

    const unsigned int P = s_prefix;
    const int r = s_r;
    for (int i = tid; i < NUM_NODES; i += 256) {
        unsigned int k = keys[i];
        if (k > P) {
            int pos = atomicAdd(&cnt_gt, 1);
            Mtop[bh*UTOP + pos] = i;
        } else if (k == P) {
            int pos = atomicAdd(&cnt_tie, 1);
            tiebuf[pos] = i;
        }
    }
    __syncthreads();
    const int ngt = cnt_gt;
    const int T = cnt_tie;
    for (int j = tid; j < T; j += 256) {
        int idx = tiebuf[j];
        int rank = 0;
        for (int t = 0; t < T; ++t) rank += (tiebuf[t] < idx) ? 1 : 0;
        if (rank < r) Mtop[bh*UTOP + ngt + rank] = idx;
    }
}

// ---------------- Kernel 5: scores + softmax + threshold, 2 u's per block ----------------
__global__ __launch_bounds__(256) void attn_kernel(
    const float* __restrict__ q, const float* __restrict__ k,
    const int* __restrict__ Mtop, float* __restrict__ attn)
{
    __shared__ float qsel0[DHEAD], qsel1[DHEAD];
    __shared__ float sc0[NUM_NODES], sc1[NUM_NODES];   // 16KB
    __shared__ float red[16];
    const int blk = blockIdx.x;              // (b*8+h)*20 + upair
    const int bh = blk / (UTOP/2), upair = blk % (UTOP/2);
    const int b = bh >> 3, h = bh & 7;
    const int u0 = upair * 2, u1 = u0 + 1;
    const int tid = threadIdx.x;
    if (tid < DHEAD) {
        const int l0 = Mtop[bh*UTOP + u0];
        const int l1 = Mtop[bh*UTOP + u1];
        qsel0[tid] = q[(size_t)(b*NUM_NODES + l0)*HID + h*DHEAD + tid];
        qsel1[tid] = q[(size_t)(b*NUM_NODES + l1)*HID + h*DHEAD + tid];
    }
    __syncthreads();
    const float scale = 0.17677669529663687f; // 1/sqrt(32)
    float lmax0 = -INFINITY, lmax1 = -INFINITY;
    for (int j = tid; j < NUM_NODES; j += 256) {
        const float4* kp = (const float4*)(k + (size_t)(b*NUM_NODES + j)*HID + h*DHEAD);
        const float4* q0 = (const float4*)qsel0;
        const float4* q1 = (const float4*)qsel1;
        float a0 = 0.f, a1 = 0.f;
        #pragma unroll
        for (int d4 = 0; d4 < 8; ++d4) {
            float4 kv = kp[d4];
            float4 v0 = q0[d4], v1 = q1[d4];
            a0 += v0.x*kv.x + v0.y*kv.y + v0.z*kv.z + v0.w*kv.w;
            a1 += v1.x*kv.x + v1.y*kv.y + v1.z*kv.z + v1.w*kv.w;
        }
        a0 *= scale; a1 *= scale;
        sc0[j] = a0; sc1[j] = a1;
        lmax0 = fmaxf(lmax0, a0);
        lmax1 = fmaxf(lmax1, a1);
    }
    #pragma unroll
    for (int m = 32; m >= 1; m >>= 1) {
        lmax0 = fmaxf(lmax0, __shfl_xor(lmax0, m));
        lmax1 = fmaxf(lmax1, __shfl_xor(lmax1, m));
    }
    if ((tid & 63) == 0) { red[tid >> 6] = lmax0; red[4 + (tid >> 6)] = lmax1; }
    __syncthreads();
    const float gmax0 = fmaxf(fmaxf(red[0], red[1]), fmaxf(red[2], red[3]));
    const float gmax1 = fmaxf(fmaxf(red[4], red[5]), fmaxf(red[6], red[7]));
    float lsum0 = 0.f, lsum1 = 0.f;
    for (int j = tid; j < NUM_NODES; j += 256) {
        float e0 = expf(sc0[j] - gmax0);
        float e1 = expf(sc1[j] - gmax1);
        sc0[j] = e0; sc1[j] = e1;
        lsum0 += e0; lsum1 += e1;
    }
    #pragma unroll
    for (int m = 32; m >= 1; m >>= 1) {
        lsum0 += __shfl_xor(lsum0, m);
        lsum1 += __shfl_xor(lsum1, m);
    }
    if ((tid & 63) == 0) { red[8 + (tid >> 6)] = lsum0; red[12 + (tid >> 6)] = lsum1; }
    __syncthreads();
    const float rinv0 = 1.0f / (red[8] + red[9] + red[10] + red[11]);
    const float rinv1 = 1.0f / (red[12] + red[13] + red[14] + red[15]);
    const float thr = 1.0f / (float)NUM_NODES;
    float* a0p = attn + (size_t)(bh*UTOP + u0)*NUM_NODES;
    float* a1p = attn + (size_t)(bh*UTOP + u1)*NUM_NODES;
    for (int j4 = tid; j4 < NUM_NODES/4; j4 += 256) {
        float4 v0, v1;
        v0.x = sc0[j4*4+0]*rinv0; if (v0.x < thr) v0.x = 0.f;
        v0.y = sc0[j4*4+1]*rinv0; if (v0.y < thr) v0.y = 0.f;
        v0.z = sc0[j4*4+2]*rinv0; if (v0.z < thr) v0.z = 0.f;
        v0.w = sc0[j4*4+3]*rinv0; if (v0.w < thr) v0.w = 0.f;
        v1.x = sc1[j4*4+0]*rinv1; if (v1.x < thr) v1.x = 0.f;
        v1.y = sc1[j4*4+1]*rinv1; if (v1.y < thr) v1.y = 0.f;
        v1.z = sc1[j4*4+2]*rinv1; if (v1.z < thr) v1.z = 0.f;
        v1.w = sc1[j4*4+3]*rinv1; if (v1.w < thr) v1.w = 0.f;
        *(float4*)(a0p + j4*4) = v0;
        *(float4*)(a1p + j4*4) = v1;
    }
}

// ---------------- Kernel 6: combine heads -> output (scans Mtop directly) ----------------
__global__ __launch_bounds__(256) void combine_kernel(
    const float* __restrict__ attn, const int* __restrict__ Mtop,
    float* __restrict__ out)
{
    __shared__ int mtops[NHEAD*UTOP];
    __shared__ int us[NHEAD];
    const int bl = blockIdx.x;  // b*2048+l
    const int b = bl >> 11, l = bl & (NUM_NODES-1);
    const int tid = threadIdx.x;
    if (tid < NHEAD) us[tid] = -1;
    for (int i = tid; i < NHEAD*UTOP; i += 256) mtops[i] = Mtop[b*NHEAD*UTOP + i];
    __syncthreads();
    for (int i = tid; i < NHEAD*UTOP; i += 256) {
        if (mtops[i] == l) us[i / UTOP] = i % UTOP;
    }
    __syncthreads();
    const size_t outbase = (size_t)bl * NUM_NODES;
    for (int j4 = tid; j4 < NUM_NODES/4; j4 += 256) {
        float4 s = make_float4(0.f, 0.f, 0.f, 0.f);
        #pragma unroll
        for (int h = 0; h < NHEAD; ++h) {
            int u = us[h];
            if (u >= 0) {
                float4 a = *(const float4*)(attn + (size_t)((b*NHEAD + h)*UTOP + u)*NUM_NODES + j4*4);
                s.x += a.x; s.y += a.y; s.z += a.z; s.w += a.w;
            }
        }
        s.x *= 0.125f; s.y *= 0.125f; s.z *= 0.125f; s.w *= 0.125f;
        *(float4*)(out + outbase + j4*4) = s;
    }
}

extern "C" void kernel_launch(void* const* d_in, const int* in_sizes, int n_in,
                              void* d_out, int out_size, void* d_ws, size_t ws_size,
                              hipStream_t stream) {
    const float* x      = (const float*)d_in[0];
    const float* w0     = (const float*)d_in[1];
    const float* b0     = (const float*)d_in[2];
    const float* w1     = (const float*)d_in[3];
    const float* b1     = (const float*)d_in[4];
    const float* w2     = (const float*)d_in[5];
    const float* b2     = (const float*)d_in[6];
    const float* g0     = (const float*)d_in[7];
    const float* be0    = (const float*)d_in[8];
    const float* g1     = (const float*)d_in[9];
    const float* be1    = (const float*)d_in[10];
    const float* g2     = (const float*)d_in[11];
    const float* be2    = (const float*)d_in[12];
    const float* g3     = (const float*)d_in[13];
    const float* be3    = (const float*)d_in[14];
    const float* fc_w   = (const float*)d_in[15];
    const float* fc_b   = (const float*)d_in[16];
    const float* q_w    = (const float*)d_in[17];
    const float* q_b    = (const float*)d_in[18];
    const float* k_w    = (const float*)d_in[19];
    const float* k_b    = (const float*)d_in[20];
    const int* idx_g    = (const int*)d_in[21];
    float* out = (float*)d_out;

    float* Hflat   = (float*)d_ws;                       // 4096*608
    float* q_ws    = Hflat + (size_t)ROWS*FCIN;          // 4096*256
    float* k_ws    = q_ws + (size_t)ROWS*HID;            // 4096*256
    float* M_ws    = k_ws + (size_t)ROWS*HID;            // 2*8*2048
    float* attn_ws = M_ws + (size_t)BATCH*NHEAD*NUM_NODES;   // 2*8*40*2048
    int*   Mtop    = (int*)(attn_ws + (size_t)BATCH*NHEAD*UTOP*NUM_NODES); // 640
    float* fc_wT   = (float*)(Mtop + BATCH*NHEAD*UTOP);  // 608*256
    float* q_wT    = fc_wT + (size_t)FCIN*HID;           // 256*256
    float* k_wT    = q_wT + (size_t)HID*HID;             // 256*256

    {
        dim3 tgrid((FCIN + 31)/32, (HID + 31)/32, 3);
        transpose3_kernel<<<tgrid, 256, 0, stream>>>(fc_w, q_w, k_w, fc_wT, q_wT, k_wT);
    }
    conv_chain_kernel<<<ROWS/4, 256, 0, stream>>>(x, w0, b0, w1, b1, w2, b2,
                                                  g0, be0, g1, be1, g2, be2, Hflat);
    fc_qk_kernel<<<ROWS/16, 512, 0, stream>>>(Hflat, fc_wT, fc_b, g3, be3,
                                              q_wT, q_b, k_wT, k_b, q_ws, k_ws);
    qk_sample_kernel<<<BATCH*NUM_NODES, 256, 0, stream>>>(q_ws, k_ws, idx_g, M_ws);
    topk_kernel<<<BATCH*NHEAD, 256, 0, stream>>>(M_ws, Mtop);
    attn_kernel<<<BATCH*NHEAD*UTOP/2, 256, 0, stream>>>(q_ws, k_ws, Mtop, attn_ws);
    combine_kernel<<<BATCH*NUM_NODES, 256, 0, stream>>>(attn_ws, Mtop, out);
}

// Round 15
// 153.069 us; speedup vs baseline: 1.0355x; 1.0355x over previous
//
#include <hip/hip_runtime.h>
#include <math.h>

#define NUM_NODES 2048
#define BATCH 2
#define NHEAD 8
#define SEQ 168
#define HID 256
#define DHEAD 32
#define UPART 80
#define UTOP 40
#define L0C 81
#define L1C 39
#define L2C 19
#define C0 8
#define C1 16
#define C2 32
#define FCIN 608   // 32*19
#define ROWS 4096  // BATCH*NUM_NODES

// ---------------- Kernel 0: transpose the three weight matrices ----------------
__global__ __launch_bounds__(256) void transpose3_kernel(
    const float* __restrict__ fc_w, const float* __restrict__ q_w, const float* __restrict__ k_w,
    float* __restrict__ fc_wT, float* __restrict__ q_wT, float* __restrict__ k_wT)
{
    __shared__ float t[32][33];
    const int z = blockIdx.z;
    const float* in = (z == 0) ? fc_w : ((z == 1) ? q_w : k_w);
    float* out      = (z == 0) ? fc_wT : ((z == 1) ? q_wT : k_wT);
    const int M = 256;
    const int N = (z == 0) ? FCIN : HID;
    const int bx = blockIdx.x * 32;
    const int by = blockIdx.y * 32;
    if (bx >= N) return;
    const int tx = threadIdx.x & 31, ty0 = threadIdx.x >> 5;
    for (int i = ty0; i < 32; i += 8) {
        int r = by + i, c = bx + tx;
        if (r < M && c < N) t[i][tx] = in[(size_t)r * N + c];
    }
    __syncthreads();
    for (int i = ty0; i < 32; i += 8) {
        int r = bx + i, c = by + tx;
        if (r < N && c < M) out[(size_t)r * M + c] = t[tx][i];
    }
}

// ---------------- Kernel 1: conv chain, ONE WAVE PER ROW, paired-t windows ----------------
// Each lane computes two adjacent outputs (t, t+1) per iteration so their
// stride-2 conv windows share LDS reads (~30% fewer LDS instructions).
#define XS_OFF 0
#define H0_OFF 168            // 8 ch x stride 82 = 656
#define H0_STR 82
#define H1_OFF (168+656)      // 16 ch x stride 40 = 640
#define H1_STR 40
#define H2_OFF (168+656+640)  // 32 ch x stride 20 = 640
#define H2_STR 20
#define WAVE_LDS 2112
__global__ __launch_bounds__(256) void conv_chain_kernel(
    const float* __restrict__ x,
    const float* __restrict__ w0, const float* __restrict__ b0,
    const float* __restrict__ w1, const float* __restrict__ b1,
    const float* __restrict__ w2, const float* __restrict__ b2,
    const float* __restrict__ g0, const float* __restrict__ be0,
    const float* __restrict__ g1, const float* __restrict__ be1,
    const float* __restrict__ g2, const float* __restrict__ be2,
    float* __restrict__ Hout)
{
    __shared__ float lds[4][WAVE_LDS];
    const int tid  = threadIdx.x;
    const int lane = tid & 63;
    const int wave = tid >> 6;
    const int row  = blockIdx.x * 4 + wave;
    float* W = lds[wave];

    {
        const float4* xp = (const float4*)(x + (size_t)row * SEQ);
        if (lane < SEQ/4) *(float4*)&W[XS_OFF + lane*4] = xp[lane];
    }

    // ---- conv0 (1->8, k=7, s=2) + relu: pairs (t0, t0+1), t0 = 2*sub + 16i ----
    {
        const int c = lane >> 3, sub = lane & 7;
        float wr[7];
        #pragma unroll
        for (int j = 0; j < 7; ++j) wr[j] = w0[c*7 + j];
        const float bias = b0[c];
        for (int t0 = 2*sub; t0 < L0C; t0 += 16) {
            const float* xp = &W[XS_OFF + 2*t0];
            float2 a = *(const float2*)(xp);
            float2 b = *(const float2*)(xp+2);
            float2 d = *(const float2*)(xp+4);
            float2 e = *(const float2*)(xp+6);
            float o0 = bias + wr[0]*a.x + wr[1]*a.y + wr[2]*b.x + wr[3]*b.y
                            + wr[4]*d.x + wr[5]*d.y + wr[6]*e.x;
            W[H0_OFF + c*H0_STR + t0] = fmaxf(o0, 0.f);
            if (t0 + 1 < L0C) {
                float g = xp[8];
                float o1 = bias + wr[0]*b.x + wr[1]*b.y + wr[2]*d.x + wr[3]*d.y
                                + wr[4]*e.x + wr[5]*e.y + wr[6]*g;
                W[H0_OFF + c*H0_STR + t0 + 1] = fmaxf(o1, 0.f);
            }
        }
    }
    // ---- LN0 over 81 per channel: 8 lanes/ch ----
    {
        const int c = lane >> 3, sub = lane & 7;
        float s = 0.f, s2 = 0.f;
        for (int t = sub; t < L0C; t += 8) { float v = W[H0_OFF + c*H0_STR + t]; s += v; s2 += v*v; }
        #pragma unroll
        for (int m = 4; m >= 1; m >>= 1) { s += __shfl_xor(s, m); s2 += __shfl_xor(s2, m); }
        float mean = s / (float)L0C;
        float inv  = rsqrtf(s2 / (float)L0C - mean*mean + 1e-5f);
        for (int t = sub; t < L0C; t += 8)
            W[H0_OFF + c*H0_STR + t] = (W[H0_OFF + c*H0_STR + t] - mean) * inv * g0[t] + be0[t];
    }
    // ---- conv1 (8->16, k=5, s=2) + relu: pairs (t0, t0+1), t0 = 2*sub + 8i ----
    {
        const int c = lane >> 2, sub = lane & 3;
        float wr[40];
        {
            const float4* wp = (const float4*)(w1 + c*40);
            #pragma unroll
            for (int j4 = 0; j4 < 10; ++j4) {
                float4 v = wp[j4];
                wr[j4*4+0] = v.x; wr[j4*4+1] = v.y; wr[j4*4+2] = v.z; wr[j4*4+3] = v.w;
            }
        }
        const float bias = b1[c];
        for (int t0 = 2*sub; t0 < L1C; t0 += 8) {
            const bool has1 = (t0 + 1 < L1C);
            float o0 = bias, o1 = bias;
            #pragma unroll
            for (int ci = 0; ci < C0; ++ci) {
                const float* hp = &W[H0_OFF + ci*H0_STR + 2*t0];
                float2 a = *(const float2*)(hp);
                float2 b = *(const float2*)(hp+2);
                float2 d = *(const float2*)(hp+4);
                o0 += wr[ci*5+0]*a.x + wr[ci*5+1]*a.y + wr[ci*5+2]*b.x
                    + wr[ci*5+3]*b.y + wr[ci*5+4]*d.x;
                if (has1) {
                    float e6 = hp[6];
                    o1 += wr[ci*5+0]*b.x + wr[ci*5+1]*b.y + wr[ci*5+2]*d.x
                        + wr[ci*5+3]*d.y + wr[ci*5+4]*e6;
                }
            }
            W[H1_OFF + c*H1_STR + t0] = fmaxf(o0, 0.f);
            if (has1) W[H1_OFF + c*H1_STR + t0 + 1] = fmaxf(o1, 0.f);
        }
    }
    // ---- LN1 over 39 per channel: 4 lanes/ch ----
    {
        const int c = lane >> 2, sub = lane & 3;
        float s = 0.f, s2 = 0.f;
        for (int t = sub; t < L1C; t += 4) { float v = W[H1_OFF + c*H1_STR + t]; s += v; s2 += v*v; }
        #pragma unroll
        for (int m = 2; m >= 1; m >>= 1) { s += __shfl_xor(s, m); s2 += __shfl_xor(s2, m); }
        float mean = s / (float)L1C;
        float inv  = rsqrtf(s2 / (float)L1C - mean*mean + 1e-5f);
        for (int t = sub; t < L1C; t += 4)
            W[H1_OFF + c*H1_STR + t] = (W[H1_OFF + c*H1_STR + t] - mean) * inv * g1[t] + be1[t];
    }
    // ---- conv2 (16->32, k=3, s=2) + relu: pairs (t0, t0+1), t0 = 2*sub + 4i ----
    {
        const int c = lane >> 1, sub = lane & 1;
        float wr[48];
        {
            const float4* wp = (const float4*)(w2 + c*48);
            #pragma unroll
            for (int j4 = 0; j4 < 12; ++j4) {
                float4 v = wp[j4];
                wr[j4*4+0] = v.x; wr[j4*4+1] = v.y; wr[j4*4+2] = v.z; wr[j4*4+3] = v.w;
            }
        }
        const float bias = b2[c];
        for (int t0 = 2*sub; t0 < L2C; t0 += 4) {
            const bool has1 = (t0 + 1 < L2C);
            float o0 = bias, o1 = bias;
            #pragma unroll
            for (int ci = 0; ci < C1; ++ci) {
                const float* hp = &W[H1_OFF + ci*H1_STR + 2*t0];
                float2 a = *(const float2*)(hp);
                float2 d = *(const float2*)(hp+2);
                o0 += wr[ci*3+0]*a.x + wr[ci*3+1]*a.y + wr[ci*3+2]*d.x;
                if (has1) {
                    float e4 = hp[4];
                    o1 += wr[ci*3+0]*d.x + wr[ci*3+1]*d.y + wr[ci*3+2]*e4;
                }
            }
            W[H2_OFF + c*H2_STR + t0] = fmaxf(o0, 0.f);
            if (has1) W[H2_OFF + c*H2_STR + t0 + 1] = fmaxf(o1, 0.f);
        }
    }
    // ---- LN2 over 19 per channel: 2 lanes/ch ----
    {
        const int c = lane >> 1, sub = lane & 1;
        float s = 0.f, s2 = 0.f;
        for (int t = sub; t < L2C; t += 2) { float v = W[H2_OFF + c*H2_STR + t]; s += v; s2 += v*v; }
        s += __shfl_xor(s, 1); s2 += __shfl_xor(s2, 1);
        float mean = s / (float)L2C;
        float inv  = rsqrtf(s2 / (float)L2C - mean*mean + 1e-5f);
        for (int t = sub; t < L2C; t += 2)
            W[H2_OFF + c*H2_STR + t] = (W[H2_OFF + c*H2_STR + t] - mean) * inv * g2[t] + be2[t];
    }
    for (int i = lane; i < FCIN; i += 64) {
        int c = i / L2C, t = i - c*L2C;
        Hout[(size_t)row*FCIN + i] = W[H2_OFF + c*H2_STR + t];
    }
}

// ---------------- Kernel 2: fc+relu+LN3 + q,k projections (R12-measured best) ----------------
// R6 structure + full 16-row H tile staged in LDS (contiguous 38.9KB, coalesced).
__global__ __launch_bounds__(512) void fc_qk_kernel(
    const float* __restrict__ Hin,
    const float* __restrict__ fc_wT, const float* __restrict__ fc_b,
    const float* __restrict__ g3, const float* __restrict__ be3,
    const float* __restrict__ q_wT, const float* __restrict__ q_b,
    const float* __restrict__ k_wT, const float* __restrict__ k_b,
    float* __restrict__ q_out, float* __restrict__ k_out)
{
    __shared__ float Hlds[16][FCIN];    // 38.9KB: staged H tile
    __shared__ float part[3][16][HID];  // 48KB: partials from kh=1..3
    __shared__ float hm[16][HID];       // 16KB: activations

    const int tid  = threadIdx.x;
    const int lane = tid & 63;
    const int wave = tid >> 6;
    const int cg   = __builtin_amdgcn_readfirstlane(wave & 1);   // col group 0/1
    const int kh   = __builtin_amdgcn_readfirstlane(wave >> 1);  // k quarter 0..3
    const int c0   = cg * 128 + lane * 2;                        // 2 contiguous cols
    const int r0   = blockIdx.x * 16;

    // ---------- stage H tile (rows r0..r0+15 are contiguous in memory) ----------
    {
        const float4* src = (const float4*)(Hin + (size_t)r0 * FCIN);
        float4* dst = (float4*)&Hlds[0][0];
        for (int i4 = tid; i4 < 16*FCIN/4; i4 += 512) dst[i4] = src[i4];
    }
    __syncthreads();   // S0

    float2 acc[16];

    // ---------- fc partial over this wave's k-quarter ----------
    #pragma unroll
    for (int r = 0; r < 16; ++r) acc[r] = make_float2(0.f, 0.f);
    {
        const int kbeg = kh * (FCIN/4), kend = kbeg + FCIN/4;
        for (int k = kbeg; k < kend; k += 4) {
            float2 w0 = *(const float2*)(fc_wT + (size_t)(k+0)*HID + c0);
            float2 w1 = *(const float2*)(fc_wT + (size_t)(k+1)*HID + c0);
            float2 w2 = *(const float2*)(fc_wT + (size_t)(k+2)*HID + c0);
            float2 w3 = *(const float2*)(fc_wT + (size_t)(k+3)*HID + c0);
            #pragma unroll
            for (int r = 0; r < 16; ++r) {
                float4 h4 = *(const float4*)&Hlds[r][k];
                acc[r].x += h4.x*w0.x + h4.y*w1.x + h4.z*w2.x + h4.w*w3.x;
                acc[r].y += h4.x*w0.y + h4.y*w1.y + h4.z*w2.y + h4.w*w3.y;
            }
        }
    }
    if (kh != 0) {
        #pragma unroll
        for (int r = 0; r < 16; ++r) *(float2*)&part[kh-1][r][c0] = acc[r];
    }
    __syncthreads();   // S1

    // ---------- reduce + bias + relu -> hm (kh==0 waves) ----------
    if (kh == 0) {
        float2 b2v = *(const float2*)(fc_b + c0);
        #pragma unroll
        for (int r = 0; r < 16; ++r) {
            float2 p0 = *(const float2*)&part[0][r][c0];
            float2 p1 = *(const float2*)&part[1][r][c0];
            float2 p2 = *(const float2*)&part[2][r][c0];
            float2 e;
            e.x = fmaxf(acc[r].x + p0.x + p1.x + p2.x + b2v.x, 0.f);
            e.y = fmaxf(acc[r].y + p0.y + p1.y + p2.y + b2v.y, 0.f);
            *(float2*)&hm[r][c0] = e;
        }
    }
    __syncthreads();   // S2

    // ---------- LN3: wave handles rows 2*wave, 2*wave+1 ----------
    {
        float4 gg = *(const float4*)(g3 + lane*4);
        float4 bb = *(const float4*)(be3 + lane*4);
        #pragma unroll
        for (int rr = 0; rr < 2; ++rr) {
            const int row = wave*2 + rr;
            float4 v = *(const float4*)&hm[row][lane*4];
            float s  = v.x + v.y + v.z + v.w;
            float s2 = v.x*v.x + v.y*v.y + v.z*v.z + v.w*v.w;
            #pragma unroll
            for (int m = 32; m >= 1; m >>= 1) { s += __shfl_xor(s, m); s2 += __shfl_xor(s2, m); }
            float mean = s * (1.f/256.f);
            float inv  = rsqrtf(s2 * (1.f/256.f) - mean*mean + 1e-5f);
            v.x = (v.x - mean) * inv * gg.x + bb.x;
            v.y = (v.y - mean) * inv * gg.y + bb.y;
            v.z = (v.z - mean) * inv * gg.z + bb.z;
            v.w = (v.w - mean) * inv * gg.w + bb.w;
            *(float4*)&hm[row][lane*4] = v;
        }
    }
    __syncthreads();   // S3

    // ---------- q projection ----------
    #pragma unroll
    for (int r = 0; r < 16; ++r) acc[r] = make_float2(0.f, 0.f);
    {
        const int kbeg = kh * (HID/4), kend = kbeg + HID/4;
        for (int k = kbeg; k < kend; k += 4) {
            float2 w0 = *(const float2*)(q_wT + (size_t)(k+0)*HID + c0);
            float2 w1 = *(const float2*)(q_wT + (size_t)(k+1)*HID + c0);
            float2 w2 = *(const float2*)(q_wT + (size_t)(k+2)*HID + c0);
            float2 w3 = *(const float2*)(q_wT + (size_t)(k+3)*HID + c0);
            #pragma unroll
            for (int r = 0; r < 16; ++r) {
                float4 h4 = *(const float4*)&hm[r][k];
                acc[r].x += h4.x*w0.x + h4.y*w1.x + h4.z*w2.x + h4.w*w3.x;
                acc[r].y += h4.x*w0.y + h4.y*w1.y + h4.z*w2.y + h4.w*w3.y;
            }
        }
    }
    if (kh != 0) {
        #pragma unroll
        for (int r = 0; r < 16; ++r) *(float2*)&part[kh-1][r][c0] = acc[r];
    }
    __syncthreads();   // S4
    if (kh == 0) {
        float2 b2v = *(const float2*)(q_b + c0);
        #pragma unroll
        for (int r = 0; r < 16; ++r) {
            float2 p0 = *(const float2*)&part[0][r][c0];
            float2 p1 = *(const float2*)&part[1][r][c0];
            float2 p2 = *(const float2*)&part[2][r][c0];
            float2 o;
            o.x = acc[r].x + p0.x + p1.x + p2.x + b2v.x;
            o.y = acc[r].y + p0.y + p1.y + p2.y + b2v.y;
            *(float2*)(q_out + (size_t)(r0 + r)*HID + c0) = o;
        }
    }

    // ---------- k projection (compute first; barrier before part rewrite) ----------
    #pragma unroll
    for (int r = 0; r < 16; ++r) acc[r] = make_float2(0.f, 0.f);
    {
        const int kbeg = kh * (HID/4), kend = kbeg + HID/4;
        for (int k = kbeg; k < kend; k += 4) {
            float2 w0 = *(const float2*)(k_wT + (size_t)(k+0)*HID + c0);
            float2 w1 = *(const float2*)(k_wT + (size_t)(k+1)*HID + c0);
            float2 w2 = *(const float2*)(k_wT + (size_t)(k+2)*HID + c0);
            float2 w3 = *(const float2*)(k_wT + (size_t)(k+3)*HID + c0);
            #pragma unroll
            for (int r = 0; r < 16; ++r) {
                float4 h4 = *(const float4*)&hm[r][k];
                acc[r].x += h4.x*w0.x + h4.y*w1.x + h4.z*w2.x + h4.w*w3.x;
                acc[r].y += h4.x*w0.y + h4.y*w1.y + h4.z*w2.y + h4.w*w3.y;
            }
        }
    }
    __syncthreads();   // S5: kh0 done reading q partials
    if (kh != 0) {
        #pragma unroll
        for (int r = 0; r < 16; ++r) *(float2*)&part[kh-1][r][c0] = acc[r];
    }
    __syncthreads();   // S6
    if (kh == 0) {
        float2 b2v = *(const float2*)(k_b + c0);
        #pragma unroll
        for (int r = 0; r < 16; ++r) {
            float2 p0 = *(const float2*)&part[0][r][c0];
            float2 p1 = *(const float2*)&part[1][r][c0];
            float2 p2 = *(const float2*)&part[2][r][c0];
            float2 o;
            o.x = acc[r].x + p0.x + p1.x + p2.x + b2v.x;
            o.y = acc[r].y + p0.y + p1.y + p2.y + b2v.y;
            *(float2*)(k_out + (size_t)(r0 + r)*HID + c0) = o;
        }
    }
}

// ---------------- Kernel 3: QK_sample + M ----------------
__global__ __launch_bounds__(256) void qk_sample_kernel(
    const float* __restrict__ q, const float* __restrict__ k,
    const int* __restrict__ idx_g, float* __restrict__ M)
{
    __shared__ int sidx[UPART];
    __shared__ float qrow[HID];
    __shared__ float qk[NHEAD][UPART];
    const int bl = blockIdx.x;            // b*2048 + l
    const int b = bl >> 11, l = bl & (NUM_NODES-1);
    const int tid = threadIdx.x;
    if (tid < UPART) sidx[tid] = idx_g[l*UPART + tid];
    qrow[tid] = q[(size_t)bl*HID + tid];
    __syncthreads();
    for (int task = tid; task < NHEAD*UPART; task += 256) {
        int h = task / UPART, s = task % UPART;
        const float4* kp = (const float4*)(k + (size_t)(b*NUM_NODES + sidx[s])*HID + h*DHEAD);
        const float4* qp = (const float4*)(qrow + h*DHEAD);
        float acc = 0.f;
        #pragma unroll
        for (int d4 = 0; d4 < 8; ++d4) {
            float4 kv = kp[d4], qv = qp[d4];
            acc += qv.x*kv.x + qv.y*kv.y + qv.z*kv.z + qv.w*kv.w;
        }
        qk[h][s] = acc;
    }
    __syncthreads();
    {
        const int h = tid >> 5, sub = tid & 31;
        float mx = -INFINITY, sm = 0.f;
        for (int s = sub; s < UPART; s += 32) { float v = qk[h][s]; mx = fmaxf(mx, v); sm += v; }
        #pragma unroll
        for (int m = 16; m >= 1; m >>= 1) {
            mx = fmaxf(mx, __shfl_xor(mx, m));
            sm += __shfl_xor(sm, m);
        }
        if (sub == 0)
            M[(size_t)(b*NHEAD + h)*NUM_NODES + l] = mx - sm / (float)NUM_NODES;
    }
}

// ---------------- Kernel 4: top-40 per (b,h) via 4-round radix select ----------------
__global__ __launch_bounds__(256) void topk_kernel(
    const float* __restrict__ M, int* __restrict__ Mtop)
{
    __shared__ unsigned int keys[NUM_NODES];
    __shared__ unsigned int hist[256];
    __shared__ int tiebuf[NUM_NODES];
    __shared__ int cnt_gt, cnt_tie;
    __shared__ unsigned int s_prefix;
    __shared__ int s_r;

    const int bh = blockIdx.x;
    const int tid = threadIdx.x;

    for (int i = tid; i < NUM_NODES; i += 256) {
        unsigned int u = __float_as_uint(M[(size_t)bh*NUM_NODES + i]);
        keys[i] = (u & 0x80000000u) ? ~u : (u | 0x80000000u);
    }
    if (tid == 0) { s_prefix = 0u; s_r = UTOP; cnt_gt = 0; cnt_tie = 0; }
    __syncthreads();

    for (int shift = 24; shift >= 0; shift -= 8) {
        hist[tid] = 0u;
        __syncthreads();
        const unsigned int prefix = s_prefix;
        const unsigned int pmask = (shift == 24) ? 0u : ~((1u << (shift + 8)) - 1u);
        for (int i = tid; i < NUM_NODES; i += 256) {
            unsigned int k = keys[i];
            if ((k & pmask) == prefix)
                atomicAdd(&hist[(k >> shift) & 0xFFu], 1u);
        }
        __syncthreads();
        if (tid < 64) {
            const int b0 = 255 - tid * 4;
            unsigned int c0 = hist[b0], c1 = hist[b0-1], c2 = hist[b0-2], c3 = hist[b0-3];
            unsigned int gsum = c0 + c1 + c2 + c3;
            unsigned int pre = gsum;
            #pragma unroll
            for (int d = 1; d < 64; d <<= 1) {
                unsigned int o = __shfl_up(pre, d);
                if (tid >= d) pre += o;
            }
            pre -= gsum;
            const unsigned int r = (unsigned int)s_r;
            unsigned int ca0 = pre, ca1 = ca0 + c0, ca2 = ca1 + c1, ca3 = ca2 + c2;
            if (ca0 < r && r <= ca0 + c0) { s_prefix = prefix | ((unsigned int)(b0  ) << shift); s_r = (int)(r - ca0); }
            if (ca1 < r && r <= ca1 + c1) { s_prefix = prefix | ((unsigned int)(b0-1) << shift); s_r = (int)(r - ca1); }
            if (ca2 < r && r <= ca2 + c2) { s_prefix = prefix | ((unsigned int)(b0-2) << shift); s_r = (int)(r - ca2); }
            if (ca3 < r && r <= ca3 + c3) { s_prefix = prefix | ((unsigned int)(b0-3) << shift); s_r = (int)(r - ca3); }
        }
        __syncthreads();
    }

    const unsigned int P = s_prefix;
    const int r = s_r;
    for (int i = tid; i < NUM_NODES; i += 256) {
        unsigned int k = keys[i];
        if (k > P) {
            int pos = atomicAdd(&cnt_gt, 1);
            Mtop[bh*UTOP + pos] = i;
        } else if (k == P) {
            int pos = atomicAdd(&cnt_tie, 1);
            tiebuf[pos] = i;
        }
    }
    __syncthreads();
    const int ngt = cnt_gt;
    const int T = cnt_tie;
    for (int j = tid; j < T; j += 256) {
        int idx = tiebuf[j];
        int rank = 0;
        for (int t = 0; t < T; ++t) rank += (tiebuf[t] < idx) ? 1 : 0;
        if (rank < r) Mtop[bh*UTOP + ngt + rank] = idx;
    }
}

// ---------------- Kernel 5: scores + softmax + threshold, 2 u's per block ----------------
__global__ __launch_bounds__(256) void attn_kernel(
    const float* __restrict__ q, const float* __restrict__ k,
    const int* __restrict__ Mtop, float* __restrict__ attn)
{
    __shared__ float qsel0[DHEAD], qsel1[DHEAD];
    __shared__ float sc0[NUM_NODES], sc1[NUM_NODES];   // 16KB
    __shared__ float red[16];
    const int blk = blockIdx.x;              // (b*8+h)*20 + upair
    const int bh = blk / (UTOP/2), upair = blk % (UTOP/2);
    const int b = bh >> 3, h = bh & 7;
    const int u0 = upair * 2, u1 = u0 + 1;
    const int tid = threadIdx.x;
    if (tid < DHEAD) {
        const int l0 = Mtop[bh*UTOP + u0];
        const int l1 = Mtop[bh*UTOP + u1];
        qsel0[tid] = q[(size_t)(b*NUM_NODES + l0)*HID + h*DHEAD + tid];
        qsel1[tid] = q[(size_t)(b*NUM_NODES + l1)*HID + h*DHEAD + tid];
    }
    __syncthreads();
    const float scale = 0.17677669529663687f; // 1/sqrt(32)
    float lmax0 = -INFINITY, lmax1 = -INFINITY;
    for (int j = tid; j < NUM_NODES; j += 256) {
        const float4* kp = (const float4*)(k + (size_t)(b*NUM_NODES + j)*HID + h*DHEAD);
        const float4* q0 = (const float4*)qsel0;
        const float4* q1 = (const float4*)qsel1;
        float a0 = 0.f, a1 = 0.f;
        #pragma unroll
        for (int d4 = 0; d4 < 8; ++d4) {
            float4 kv = kp[d4];
            float4 v0 = q0[d4], v1 = q1[d4];
            a0 += v0.x*kv.x + v0.y*kv.y + v0.z*kv.z + v0.w*kv.w;
            a1 += v1.x*kv.x + v1.y*kv.y + v1.z*kv.z + v1.w*kv.w;
        }
        a0 *= scale; a1 *= scale;
        sc0[j] = a0; sc1[j] = a1;
        lmax0 = fmaxf(lmax0, a0);
        lmax1 = fmaxf(lmax1, a1);
    }
    #pragma unroll
    for (int m = 32; m >= 1; m >>= 1) {
        lmax0 = fmaxf(lmax0, __shfl_xor(lmax0, m));
        lmax1 = fmaxf(lmax1, __shfl_xor(lmax1, m));
    }
    if ((tid & 63) == 0) { red[tid >> 6] = lmax0; red[4 + (tid >> 6)] = lmax1; }
    __syncthreads();
    const float gmax0 = fmaxf(fmaxf(red[0], red[1]), fmaxf(red[2], red[3]));
    const float gmax1 = fmaxf(fmaxf(red[4], red[5]), fmaxf(red[6], red[7]));
    float lsum0 = 0.f, lsum1 = 0.f;
    for (int j = tid; j < NUM_NODES; j += 256) {
        float e0 = expf(sc0[j] - gmax0);
        float e1 = expf(sc1[j] - gmax1);
        sc0[j] = e0; sc1[j] = e1;
        lsum0 += e0; lsum1 += e1;
    }
    #pragma unroll
    for (int m = 32; m >= 1; m >>= 1) {
        lsum0 += __shfl_xor(lsum0, m);
        lsum1 += __shfl_xor(lsum1, m);
    }
    if ((tid & 63) == 0) { red[8 + (tid >> 6)] = lsum0; red[12 + (tid >> 6)] = lsum1; }
    __syncthreads();
    const float rinv0 = 1.0f / (red[8] + red[9] + red[10] + red[11]);
    const float rinv1 = 1.0f / (red[12] + red[13] + red[14] + red[15]);
    const float thr = 1.0f / (float)NUM_NODES;
    float* a0p = attn + (size_t)(bh*UTOP + u0)*NUM_NODES;
    float* a1p = attn + (size_t)(bh*UTOP + u1)*NUM_NODES;
    for (int j4 = tid; j4 < NUM_NODES/4; j4 += 256) {
        float4 v0, v1;
        v0.x = sc0[j4*4+0]*rinv0; if (v0.x < thr) v0.x = 0.f;
        v0.y = sc0[j4*4+1]*rinv0; if (v0.y < thr) v0.y = 0.f;
        v0.z = sc0[j4*4+2]*rinv0; if (v0.z < thr) v0.z = 0.f;
        v0.w = sc0[j4*4+3]*rinv0; if (v0.w < thr) v0.w = 0.f;
        v1.x = sc1[j4*4+0]*rinv1; if (v1.x < thr) v1.x = 0.f;
        v1.y = sc1[j4*4+1]*rinv1; if (v1.y < thr) v1.y = 0.f;
        v1.z = sc1[j4*4+2]*rinv1; if (v1.z < thr) v1.z = 0.f;
        v1.w = sc1[j4*4+3]*rinv1; if (v1.w < thr) v1.w = 0.f;
        *(float4*)(a0p + j4*4) = v0;
        *(float4*)(a1p + j4*4) = v1;
    }
}

// ---------------- Kernel 6: combine heads -> output (scans Mtop directly) ----------------
__global__ __launch_bounds__(256) void combine_kernel(
    const float* __restrict__ attn, const int* __restrict__ Mtop,
    float* __restrict__ out)
{
    __shared__ int mtops[NHEAD*UTOP];
    __shared__ int us[NHEAD];
    const int bl = blockIdx.x;  // b*2048+l
    const int b = bl >> 11, l = bl & (NUM_NODES-1);
    const int tid = threadIdx.x;
    if (tid < NHEAD) us[tid] = -1;
    for (int i = tid; i < NHEAD*UTOP; i += 256) mtops[i] = Mtop[b*NHEAD*UTOP + i];
    __syncthreads();
    for (int i = tid; i < NHEAD*UTOP; i += 256) {
        if (mtops[i] == l) us[i / UTOP] = i % UTOP;
    }
    __syncthreads();
    const size_t outbase = (size_t)bl * NUM_NODES;
    for (int j4 = tid; j4 < NUM_NODES/4; j4 += 256) {
        float4 s = make_float4(0.f, 0.f, 0.f, 0.f);
        #pragma unroll
        for (int h = 0; h < NHEAD; ++h) {
            int u = us[h];
            if (u >= 0) {
                float4 a = *(const float4*)(attn + (size_t)((b*NHEAD + h)*UTOP + u)*NUM_NODES + j4*4);
                s.x += a.x; s.y += a.y; s.z += a.z; s.w += a.w;
            }
        }
        s.x *= 0.125f; s.y *= 0.125f; s.z *= 0.125f; s.w *= 0.125f;
        *(float4*)(out + outbase + j4*4) = s;
    }
}

extern "C" void kernel_launch(void* const* d_in, const int* in_sizes, int n_in,
                              void* d_out, int out_size, void* d_ws, size_t ws_size,
                              hipStream_t stream) {
    const float* x      = (const float*)d_in[0];
    const float* w0     = (const float*)d_in[1];
    const float* b0     = (const float*)d_in[2];
    const float* w1     = (const float*)d_in[3];
    const float* b1     = (const float*)d_in[4];
    const float* w2     = (const float*)d_in[5];
    const float* b2     = (const float*)d_in[6];
    const float* g0     = (const float*)d_in[7];
    const float* be0    = (const float*)d_in[8];
    const float* g1     = (const float*)d_in[9];
    const float* be1    = (const float*)d_in[10];
    const float* g2     = (const float*)d_in[11];
    const float* be2    = (const float*)d_in[12];
    const float* g3     = (const float*)d_in[13];
    const float* be3    = (const float*)d_in[14];
    const float* fc_w   = (const float*)d_in[15];
    const float* fc_b   = (const float*)d_in[16];
    const float* q_w    = (const float*)d_in[17];
    const float* q_b    = (const float*)d_in[18];
    const float* k_w    = (const float*)d_in[19];
    const float* k_b    = (const float*)d_in[20];
    const int* idx_g    = (const int*)d_in[21];
    float* out = (float*)d_out;

    float* Hflat   = (float*)d_ws;                       // 4096*608
    float* q_ws    = Hflat + (size_t)ROWS*FCIN;          // 4096*256
    float* k_ws    = q_ws + (size_t)ROWS*HID;            // 4096*256
    float* M_ws    = k_ws + (size_t)ROWS*HID;            // 2*8*2048
    float* attn_ws = M_ws + (size_t)BATCH*NHEAD*NUM_NODES;   // 2*8*40*2048
    int*   Mtop    = (int*)(attn_ws + (size_t)BATCH*NHEAD*UTOP*NUM_NODES); // 640
    float* fc_wT   = (float*)(Mtop + BATCH*NHEAD*UTOP);  // 608*256
    float* q_wT    = fc_wT + (size_t)FCIN*HID;           // 256*256
    float* k_wT    = q_wT + (size_t)HID*HID;             // 256*256

    {
        dim3 tgrid((FCIN + 31)/32, (HID + 31)/32, 3);
        transpose3_kernel<<<tgrid, 256, 0, stream>>>(fc_w, q_w, k_w, fc_wT, q_wT, k_wT);
    }
    conv_chain_kernel<<<ROWS/4, 256, 0, stream>>>(x, w0, b0, w1, b1, w2, b2,
                                                  g0, be0, g1, be1, g2, be2, Hflat);
    fc_qk_kernel<<<ROWS/16, 512, 0, stream>>>(Hflat, fc_wT, fc_b, g3, be3,
                                              q_wT, q_b, k_wT, k_b, q_ws, k_ws);
    qk_sample_kernel<<<BATCH*NUM_NODES, 256, 0, stream>>>(q_ws, k_ws, idx_g, M_ws);
    topk_kernel<<<BATCH*NHEAD, 256, 0, stream>>>(M_ws, Mtop);
    attn_kernel<<<BATCH*NHEAD*UTOP/2, 256, 0, stream>>>(q_ws, k_ws, Mtop, attn_ws);
    combine_kernel<<<BATCH*NUM_NODES, 256, 0, stream>>>(attn_ws, Mtop, out);
}

// Round 16
// 150.083 us; speedup vs baseline: 1.0561x; 1.0199x over previous
//
#include <hip/hip_runtime.h>
#include <math.h>

#define NUM_NODES 2048
#define BATCH 2
#define NHEAD 8
#define SEQ 168
#define HID 256
#define DHEAD 32
#define UPART 80
#define UTOP 40
#define L0C 81
#define L1C 39
#define L2C 19
#define C0 8
#define C1 16
#define C2 32
#define FCIN 608   // 32*19
#define ROWS 4096  // BATCH*NUM_NODES

// ---------------- Kernel 0: transpose the three weight matrices ----------------
__global__ __launch_bounds__(256) void transpose3_kernel(
    const float* __restrict__ fc_w, const float* __restrict__ q_w, const float* __restrict__ k_w,
    float* __restrict__ fc_wT, float* __restrict__ q_wT, float* __restrict__ k_wT)
{
    __shared__ float t[32][33];
    const int z = blockIdx.z;
    const float* in = (z == 0) ? fc_w : ((z == 1) ? q_w : k_w);
    float* out      = (z == 0) ? fc_wT : ((z == 1) ? q_wT : k_wT);
    const int M = 256;
    const int N = (z == 0) ? FCIN : HID;
    const int bx = blockIdx.x * 32;
    const int by = blockIdx.y * 32;
    if (bx >= N) return;
    const int tx = threadIdx.x & 31, ty0 = threadIdx.x >> 5;
    for (int i = ty0; i < 32; i += 8) {
        int r = by + i, c = bx + tx;
        if (r < M && c < N) t[i][tx] = in[(size_t)r * N + c];
    }
    __syncthreads();
    for (int i = ty0; i < 32; i += 8) {
        int r = bx + i, c = by + tx;
        if (r < N && c < M) out[(size_t)r * M + c] = t[tx][i];
    }
}

// ---------------- Kernel 1: conv chain, ONE WAVE PER ROW, paired-t windows ----------------
#define XS_OFF 0
#define H0_OFF 168            // 8 ch x stride 82 = 656
#define H0_STR 82
#define H1_OFF (168+656)      // 16 ch x stride 40 = 640
#define H1_STR 40
#define H2_OFF (168+656+640)  // 32 ch x stride 20 = 640
#define H2_STR 20
#define WAVE_LDS 2112
__global__ __launch_bounds__(256) void conv_chain_kernel(
    const float* __restrict__ x,
    const float* __restrict__ w0, const float* __restrict__ b0,
    const float* __restrict__ w1, const float* __restrict__ b1,
    const float* __restrict__ w2, const float* __restrict__ b2,
    const float* __restrict__ g0, const float* __restrict__ be0,
    const float* __restrict__ g1, const float* __restrict__ be1,
    const float* __restrict__ g2, const float* __restrict__ be2,
    float* __restrict__ Hout)
{
    __shared__ float lds[4][WAVE_LDS];
    const int tid  = threadIdx.x;
    const int lane = tid & 63;
    const int wave = tid >> 6;
    const int row  = blockIdx.x * 4 + wave;
    float* W = lds[wave];

    {
        const float4* xp = (const float4*)(x + (size_t)row * SEQ);
        if (lane < SEQ/4) *(float4*)&W[XS_OFF + lane*4] = xp[lane];
    }

    // ---- conv0 (1->8, k=7, s=2) + relu: pairs (t0, t0+1) ----
    {
        const int c = lane >> 3, sub = lane & 7;
        float wr[7];
        #pragma unroll
        for (int j = 0; j < 7; ++j) wr[j] = w0[c*7 + j];
        const float bias = b0[c];
        for (int t0 = 2*sub; t0 < L0C; t0 += 16) {
            const float* xp = &W[XS_OFF + 2*t0];
            float2 a = *(const float2*)(xp);
            float2 b = *(const float2*)(xp+2);
            float2 d = *(const float2*)(xp+4);
            float2 e = *(const float2*)(xp+6);
            float o0 = bias + wr[0]*a.x + wr[1]*a.y + wr[2]*b.x + wr[3]*b.y
                            + wr[4]*d.x + wr[5]*d.y + wr[6]*e.x;
            W[H0_OFF + c*H0_STR + t0] = fmaxf(o0, 0.f);
            if (t0 + 1 < L0C) {
                float g = xp[8];
                float o1 = bias + wr[0]*b.x + wr[1]*b.y + wr[2]*d.x + wr[3]*d.y
                                + wr[4]*e.x + wr[5]*e.y + wr[6]*g;
                W[H0_OFF + c*H0_STR + t0 + 1] = fmaxf(o1, 0.f);
            }
        }
    }
    // ---- LN0 ----
    {
        const int c = lane >> 3, sub = lane & 7;
        float s = 0.f, s2 = 0.f;
        for (int t = sub; t < L0C; t += 8) { float v = W[H0_OFF + c*H0_STR + t]; s += v; s2 += v*v; }
        #pragma unroll
        for (int m = 4; m >= 1; m >>= 1) { s += __shfl_xor(s, m); s2 += __shfl_xor(s2, m); }
        float mean = s / (float)L0C;
        float inv  = rsqrtf(s2 / (float)L0C - mean*mean + 1e-5f);
        for (int t = sub; t < L0C; t += 8)
            W[H0_OFF + c*H0_STR + t] = (W[H0_OFF + c*H0_STR + t] - mean) * inv * g0[t] + be0[t];
    }
    // ---- conv1 (8->16, k=5, s=2) + relu: pairs ----
    {
        const int c = lane >> 2, sub = lane & 3;
        float wr[40];
        {
            const float4* wp = (const float4*)(w1 + c*40);
            #pragma unroll
            for (int j4 = 0; j4 < 10; ++j4) {
                float4 v = wp[j4];
                wr[j4*4+0] = v.x; wr[j4*4+1] = v.y; wr[j4*4+2] = v.z; wr[j4*4+3] = v.w;
            }
        }
        const float bias = b1[c];
        for (int t0 = 2*sub; t0 < L1C; t0 += 8) {
            const bool has1 = (t0 + 1 < L1C);
            float o0 = bias, o1 = bias;
            #pragma unroll
            for (int ci = 0; ci < C0; ++ci) {
                const float* hp = &W[H0_OFF + ci*H0_STR + 2*t0];
                float2 a = *(const float2*)(hp);
                float2 b = *(const float2*)(hp+2);
                float2 d = *(const float2*)(hp+4);
                o0 += wr[ci*5+0]*a.x + wr[ci*5+1]*a.y + wr[ci*5+2]*b.x
                    + wr[ci*5+3]*b.y + wr[ci*5+4]*d.x;
                if (has1) {
                    float e6 = hp[6];
                    o1 += wr[ci*5+0]*b.x + wr[ci*5+1]*b.y + wr[ci*5+2]*d.x
                        + wr[ci*5+3]*d.y + wr[ci*5+4]*e6;
                }
            }
            W[H1_OFF + c*H1_STR + t0] = fmaxf(o0, 0.f);
            if (has1) W[H1_OFF + c*H1_STR + t0 + 1] = fmaxf(o1, 0.f);
        }
    }
    // ---- LN1 ----
    {
        const int c = lane >> 2, sub = lane & 3;
        float s = 0.f, s2 = 0.f;
        for (int t = sub; t < L1C; t += 4) { float v = W[H1_OFF + c*H1_STR + t]; s += v; s2 += v*v; }
        #pragma unroll
        for (int m = 2; m >= 1; m >>= 1) { s += __shfl_xor(s, m); s2 += __shfl_xor(s2, m); }
        float mean = s / (float)L1C;
        float inv  = rsqrtf(s2 / (float)L1C - mean*mean + 1e-5f);
        for (int t = sub; t < L1C; t += 4)
            W[H1_OFF + c*H1_STR + t] = (W[H1_OFF + c*H1_STR + t] - mean) * inv * g1[t] + be1[t];
    }
    // ---- conv2 (16->32, k=3, s=2) + relu: pairs ----
    {
        const int c = lane >> 1, sub = lane & 1;
        float wr[48];
        {
            const float4* wp = (const float4*)(w2 + c*48);
            #pragma unroll
            for (int j4 = 0; j4 < 12; ++j4) {
                float4 v = wp[j4];
                wr[j4*4+0] = v.x; wr[j4*4+1] = v.y; wr[j4*4+2] = v.z; wr[j4*4+3] = v.w;
            }
        }
        const float bias = b2[c];
        for (int t0 = 2*sub; t0 < L2C; t0 += 4) {
            const bool has1 = (t0 + 1 < L2C);
            float o0 = bias, o1 = bias;
            #pragma unroll
            for (int ci = 0; ci < C1; ++ci) {
                const float* hp = &W[H1_OFF + ci*H1_STR + 2*t0];
                float2 a = *(const float2*)(hp);
                float2 d = *(const float2*)(hp+2);
                o0 += wr[ci*3+0]*a.x + wr[ci*3+1]*a.y + wr[ci*3+2]*d.x;
                if (has1) {
                    float e4 = hp[4];
                    o1 += wr[ci*3+0]*d.x + wr[ci*3+1]*d.y + wr[ci*3+2]*e4;
                }
            }
            W[H2_OFF + c*H2_STR + t0] = fmaxf(o0, 0.f);
            if (has1) W[H2_OFF + c*H2_STR + t0 + 1] = fmaxf(o1, 0.f);
        }
    }
    // ---- LN2 ----
    {
        const int c = lane >> 1, sub = lane & 1;
        float s = 0.f, s2 = 0.f;
        for (int t = sub; t < L2C; t += 2) { float v = W[H2_OFF + c*H2_STR + t]; s += v; s2 += v*v; }
        s += __shfl_xor(s, 1); s2 += __shfl_xor(s2, 1);
        float mean = s / (float)L2C;
        float inv  = rsqrtf(s2 / (float)L2C - mean*mean + 1e-5f);
        for (int t = sub; t < L2C; t += 2)
            W[H2_OFF + c*H2_STR + t] = (W[H2_OFF + c*H2_STR + t] - mean) * inv * g2[t] + be2[t];
    }
    for (int i = lane; i < FCIN; i += 64) {
        int c = i / L2C, t = i - c*L2C;
        Hout[(size_t)row*FCIN + i] = W[H2_OFF + c*H2_STR + t];
    }
}

// ---------------- Kernel 2: fc+relu+LN3 + q,k projections ----------------
// Single column-group layout: lane owns 4 cols (c0 = lane*4, 256 cols/wave).
// 8 waves = 4 kh x 2 rh, 8 rows/wave. Halves H LDS-broadcast reads vs the
// 2-col-group layout (LDS reads = rows x K/4 x col-groups). Weight loads are
// float4 (16B/lane, coalescing sweet spot); reduction order unchanged.
__global__ __launch_bounds__(512) void fc_qk_kernel(
    const float* __restrict__ Hin,
    const float* __restrict__ fc_wT, const float* __restrict__ fc_b,
    const float* __restrict__ g3, const float* __restrict__ be3,
    const float* __restrict__ q_wT, const float* __restrict__ q_b,
    const float* __restrict__ k_wT, const float* __restrict__ k_b,
    float* __restrict__ q_out, float* __restrict__ k_out)
{
    __shared__ float Hlds[16][FCIN];    // 38.9KB: staged H tile
    __shared__ float part[3][16][HID];  // 48KB: partials from kh=1..3
    __shared__ float hm[16][HID];       // 16KB: activations

    const int tid  = threadIdx.x;
    const int lane = tid & 63;
    const int wave = tid >> 6;
    const int rh   = __builtin_amdgcn_readfirstlane(wave & 1);   // row half 0/1
    const int kh   = __builtin_amdgcn_readfirstlane(wave >> 1);  // k quarter 0..3
    const int c0   = lane * 4;                                   // 4 contiguous cols
    const int rb   = rh * 8;                                     // local row base
    const int r0   = blockIdx.x * 16;

    // ---------- stage H tile (rows r0..r0+15 contiguous) ----------
    {
        const float4* src = (const float4*)(Hin + (size_t)r0 * FCIN);
        float4* dst = (float4*)&Hlds[0][0];
        for (int i4 = tid; i4 < 16*FCIN/4; i4 += 512) dst[i4] = src[i4];
    }
    __syncthreads();   // S0

    float4 acc[8];

    // ---------- fc partial over this wave's k-quarter, rows rb..rb+7 ----------
    #pragma unroll
    for (int r = 0; r < 8; ++r) acc[r] = make_float4(0.f, 0.f, 0.f, 0.f);
    {
        const int kbeg = kh * (FCIN/4), kend = kbeg + FCIN/4;
        for (int k = kbeg; k < kend; k += 4) {
            float4 w0 = *(const float4*)(fc_wT + (size_t)(k+0)*HID + c0);
            float4 w1 = *(const float4*)(fc_wT + (size_t)(k+1)*HID + c0);
            float4 w2 = *(const float4*)(fc_wT + (size_t)(k+2)*HID + c0);
            float4 w3 = *(const float4*)(fc_wT + (size_t)(k+3)*HID + c0);
            #pragma unroll
            for (int r = 0; r < 8; ++r) {
                float4 h4 = *(const float4*)&Hlds[rb + r][k];
                acc[r].x += h4.x*w0.x + h4.y*w1.x + h4.z*w2.x + h4.w*w3.x;
                acc[r].y += h4.x*w0.y + h4.y*w1.y + h4.z*w2.y + h4.w*w3.y;
                acc[r].z += h4.x*w0.z + h4.y*w1.z + h4.z*w2.z + h4.w*w3.z;
                acc[r].w += h4.x*w0.w + h4.y*w1.w + h4.z*w2.w + h4.w*w3.w;
            }
        }
    }
    if (kh != 0) {
        #pragma unroll
        for (int r = 0; r < 8; ++r) *(float4*)&part[kh-1][rb + r][c0] = acc[r];
    }
    __syncthreads();   // S1

    // ---------- reduce + bias + relu -> hm (kh==0 waves: rh 0/1) ----------
    if (kh == 0) {
        float4 b4 = *(const float4*)(fc_b + c0);
        #pragma unroll
        for (int r = 0; r < 8; ++r) {
            const int row = rb + r;
            float4 p0 = *(const float4*)&part[0][row][c0];
            float4 p1 = *(const float4*)&part[1][row][c0];
            float4 p2 = *(const float4*)&part[2][row][c0];
            float4 e;
            e.x = fmaxf(acc[r].x + p0.x + p1.x + p2.x + b4.x, 0.f);
            e.y = fmaxf(acc[r].y + p0.y + p1.y + p2.y + b4.y, 0.f);
            e.z = fmaxf(acc[r].z + p0.z + p1.z + p2.z + b4.z, 0.f);
            e.w = fmaxf(acc[r].w + p0.w + p1.w + p2.w + b4.w, 0.f);
            *(float4*)&hm[row][c0] = e;
        }
    }
    __syncthreads();   // S2

    // ---------- LN3: wave handles rows 2*wave, 2*wave+1 ----------
    {
        float4 gg = *(const float4*)(g3 + lane*4);
        float4 bb = *(const float4*)(be3 + lane*4);
        #pragma unroll
        for (int rr = 0; rr < 2; ++rr) {
            const int row = wave*2 + rr;
            float4 v = *(const float4*)&hm[row][lane*4];
            float s  = v.x + v.y + v.z + v.w;
            float s2 = v.x*v.x + v.y*v.y + v.z*v.z + v.w*v.w;
            #pragma unroll
            for (int m = 32; m >= 1; m >>= 1) { s += __shfl_xor(s, m); s2 += __shfl_xor(s2, m); }
            float mean = s * (1.f/256.f);
            float inv  = rsqrtf(s2 * (1.f/256.f) - mean*mean + 1e-5f);
            v.x = (v.x - mean) * inv * gg.x + bb.x;
            v.y = (v.y - mean) * inv * gg.y + bb.y;
            v.z = (v.z - mean) * inv * gg.z + bb.z;
            v.w = (v.w - mean) * inv * gg.w + bb.w;
            *(float4*)&hm[row][lane*4] = v;
        }
    }
    __syncthreads();   // S3

    // ---------- q projection ----------
    #pragma unroll
    for (int r = 0; r < 8; ++r) acc[r] = make_float4(0.f, 0.f, 0.f, 0.f);
    {
        const int kbeg = kh * (HID/4), kend = kbeg + HID/4;
        for (int k = kbeg; k < kend; k += 4) {
            float4 w0 = *(const float4*)(q_wT + (size_t)(k+0)*HID + c0);
            float4 w1 = *(const float4*)(q_wT + (size_t)(k+1)*HID + c0);
            float4 w2 = *(const float4*)(q_wT + (size_t)(k+2)*HID + c0);
            float4 w3 = *(const float4*)(q_wT + (size_t)(k+3)*HID + c0);
            #pragma unroll
            for (int r = 0; r < 8; ++r) {
                float4 h4 = *(const float4*)&hm[rb + r][k];
                acc[r].x += h4.x*w0.x + h4.y*w1.x + h4.z*w2.x + h4.w*w3.x;
                acc[r].y += h4.x*w0.y + h4.y*w1.y + h4.z*w2.y + h4.w*w3.y;
                acc[r].z += h4.x*w0.z + h4.y*w1.z + h4.z*w2.z + h4.w*w3.z;
                acc[r].w += h4.x*w0.w + h4.y*w1.w + h4.z*w2.w + h4.w*w3.w;
            }
        }
    }
    if (kh != 0) {
        #pragma unroll
        for (int r = 0; r < 8; ++r) *(float4*)&part[kh-1][rb + r][c0] = acc[r];
    }
    __syncthreads();   // S4
    if (kh == 0) {
        float4 b4 = *(const float4*)(q_b + c0);
        #pragma unroll
        for (int r = 0; r < 8; ++r) {
            const int row = rb + r;
            float4 p0 = *(const float4*)&part[0][row][c0];
            float4 p1 = *(const float4*)&part[1][row][c0];
            float4 p2 = *(const float4*)&part[2][row][c0];
            float4 o;
            o.x = acc[r].x + p0.x + p1.x + p2.x + b4.x;
            o.y = acc[r].y + p0.y + p1.y + p2.y + b4.y;
            o.z = acc[r].z + p0.z + p1.z + p2.z + b4.z;
            o.w = acc[r].w + p0.w + p1.w + p2.w + b4.w;
            *(float4*)(q_out + (size_t)(r0 + row)*HID + c0) = o;
        }
    }

    // ---------- k projection (compute first; barrier before part rewrite) ----------
    #pragma unroll
    for (int r = 0; r < 8; ++r) acc[r] = make_float4(0.f, 0.f, 0.f, 0.f);
    {
        const int kbeg = kh * (HID/4), kend = kbeg + HID/4;
        for (int k = kbeg; k < kend; k += 4) {
            float4 w0 = *(const float4*)(k_wT + (size_t)(k+0)*HID + c0);
            float4 w1 = *(const float4*)(k_wT + (size_t)(k+1)*HID + c0);
            float4 w2 = *(const float4*)(k_wT + (size_t)(k+2)*HID + c0);
            float4 w3 = *(const float4*)(k_wT + (size_t)(k+3)*HID + c0);
            #pragma unroll
            for (int r = 0; r < 8; ++r) {
                float4 h4 = *(const float4*)&hm[rb + r][k];
                acc[r].x += h4.x*w0.x + h4.y*w1.x + h4.z*w2.x + h4.w*w3.x;
                acc[r].y += h4.x*w0.y + h4.y*w1.y + h4.z*w2.y + h4.w*w3.y;
                acc[r].z += h4.x*w0.z + h4.y*w1.z + h4.z*w2.z + h4.w*w3.z;
                acc[r].w += h4.x*w0.w + h4.y*w1.w + h4.z*w2.w + h4.w*w3.w;
            }
        }
    }
    __syncthreads();   // S5: kh0 done reading q partials
    if (kh != 0) {
        #pragma unroll
        for (int r = 0; r < 8; ++r) *(float4*)&part[kh-1][rb + r][c0] = acc[r];
    }
    __syncthreads();   // S6
    if (kh == 0) {
        float4 b4 = *(const float4*)(k_b + c0);
        #pragma unroll
        for (int r = 0; r < 8; ++r) {
            const int row = rb + r;
            float4 p0 = *(const float4*)&part[0][row][c0];
            float4 p1 = *(const float4*)&part[1][row][c0];
            float4 p2 = *(const float4*)&part[2][row][c0];
            float4 o;
            o.x = acc[r].x + p0.x + p1.x + p2.x + b4.x;
            o.y = acc[r].y + p0.y + p1.y + p2.y + b4.y;
            o.z = acc[r].z + p0.z + p1.z + p2.z + b4.z;
            o.w = acc[r].w + p0.w + p1.w + p2.w + b4.w;
            *(float4*)(k_out + (size_t)(r0 + row)*HID + c0) = o;
        }
    }
}

// ---------------- Kernel 3: QK_sample + M ----------------
__global__ __launch_bounds__(256) void qk_sample_kernel(
    const float* __restrict__ q, const float* __restrict__ k,
    const int* __restrict__ idx_g, float* __restrict__ M)
{
    __shared__ int sidx[UPART];
    __shared__ float qrow[HID];
    __shared__ float qk[NHEAD][UPART];
    const int bl = blockIdx.x;            // b*2048 + l
    const int b = bl >> 11, l = bl & (NUM_NODES-1);
    const int tid = threadIdx.x;
    if (tid < UPART) sidx[tid] = idx_g[l*UPART + tid];
    qrow[tid] = q[(size_t)bl*HID + tid];
    __syncthreads();
    for (int task = tid; task < NHEAD*UPART; task += 256) {
        int h = task / UPART, s = task % UPART;
        const float4* kp = (const float4*)(k + (size_t)(b*NUM_NODES + sidx[s])*HID + h*DHEAD);
        const float4* qp = (const float4*)(qrow + h*DHEAD);
        float acc = 0.f;
        #pragma unroll
        for (int d4 = 0; d4 < 8; ++d4) {
            float4 kv = kp[d4], qv = qp[d4];
            acc += qv.x*kv.x + qv.y*kv.y + qv.z*kv.z + qv.w*kv.w;
        }
        qk[h][s] = acc;
    }
    __syncthreads();
    {
        const int h = tid >> 5, sub = tid & 31;
        float mx = -INFINITY, sm = 0.f;
        for (int s = sub; s < UPART; s += 32) { float v = qk[h][s]; mx = fmaxf(mx, v); sm += v; }
        #pragma unroll
        for (int m = 16; m >= 1; m >>= 1) {
            mx = fmaxf(mx, __shfl_xor(mx, m));
            sm += __shfl_xor(sm, m);
        }
        if (sub == 0)
            M[(size_t)(b*NHEAD + h)*NUM_NODES + l] = mx - sm / (float)NUM_NODES;
    }
}

// ---------------- Kernel 4: top-40 per (b,h) via 4-round radix select ----------------
__global__ __launch_bounds__(256) void topk_kernel(
    const float* __restrict__ M, int* __restrict__ Mtop)
{
    __shared__ unsigned int keys[NUM_NODES];
    __shared__ unsigned int hist[256];
    __shared__ int tiebuf[NUM_NODES];
    __shared__ int cnt_gt, cnt_tie;
    __shared__ unsigned int s_prefix;
    __shared__ int s_r;

    const int bh = blockIdx.x;
    const int tid = threadIdx.x;

    for (int i = tid; i < NUM_NODES; i += 256) {
        unsigned int u = __float_as_uint(M[(size_t)bh*NUM_NODES + i]);
        keys[i] = (u & 0x80000000u) ? ~u : (u | 0x80000000u);
    }
    if (tid == 0) { s_prefix = 0u; s_r = UTOP; cnt_gt = 0; cnt_tie = 0; }
    __syncthreads();

    for (int shift = 24; shift >= 0; shift -= 8) {
        hist[tid] = 0u;
        __syncthreads();
        const unsigned int prefix = s_prefix;
        const unsigned int pmask = (shift == 24) ? 0u : ~((1u << (shift + 8)) - 1u);
        for (int i = tid; i < NUM_NODES; i += 256) {
            unsigned int k = keys[i];
            if ((k & pmask) == prefix)
                atomicAdd(&hist[(k >> shift) & 0xFFu], 1u);
        }
        __syncthreads();
        if (tid < 64) {
            const int b0 = 255 - tid * 4;
            unsigned int c0 = hist[b0], c1 = hist[b0-1], c2 = hist[b0-2], c3 = hist[b0-3];
            unsigned int gsum = c0 + c1 + c2 + c3;
            unsigned int pre = gsum;
            #pragma unroll
            for (int d = 1; d < 64; d <<= 1) {
                unsigned int o = __shfl_up(pre, d);
                if (tid >= d) pre += o;
            }
            pre -= gsum;
            const unsigned int r = (unsigned int)s_r;
            unsigned int ca0 = pre, ca1 = ca0 + c0, ca2 = ca1 + c1, ca3 = ca2 + c2;
            if (ca0 < r && r <= ca0 + c0) { s_prefix = prefix | ((unsigned int)(b0  ) << shift); s_r = (int)(r - ca0); }
            if (ca1 < r && r <= ca1 + c1) { s_prefix = prefix | ((unsigned int)(b0-1) << shift); s_r = (int)(r - ca1); }
            if (ca2 < r && r <= ca2 + c2) { s_prefix = prefix | ((unsigned int)(b0-2) << shift); s_r = (int)(r - ca2); }
            if (ca3 < r && r <= ca3 + c3) { s_prefix = prefix | ((unsigned int)(b0-3) << shift); s_r = (int)(r - ca3); }
        }
        __syncthreads();
    }

    const unsigned int P = s_prefix;
    const int r = s_r;
    for (int i = tid; i < NUM_NODES; i += 256) {
        unsigned int k = keys[i];
        if (k > P) {
            int pos = atomicAdd(&cnt_gt, 1);
            Mtop[bh*UTOP + pos] = i;
        } else if (k == P) {
            int pos = atomicAdd(&cnt_tie, 1);
            tiebuf[pos] = i;
        }
    }
    __syncthreads();
    const int ngt = cnt_gt;
    const int T = cnt_tie;
    for (int j = tid; j < T; j += 256) {
        int idx = tiebuf[j];
        int rank = 0;
        for (int t = 0; t < T; ++t) rank += (tiebuf[t] < idx) ? 1 : 0;
        if (rank < r) Mtop[bh*UTOP + ngt + rank] = idx;
    }
}

// ---------------- Kernel 5: scores + softmax + threshold, 2 u's per block ----------------
__global__ __launch_bounds__(256) void attn_kernel(
    const float* __restrict__ q, const float* __restrict__ k,
    const int* __restrict__ Mtop, float* __restrict__ attn)
{
    __shared__ float qsel0[DHEAD], qsel1[DHEAD];
    __shared__ float sc0[NUM_NODES], sc1[NUM_NODES];   // 16KB
    __shared__ float red[16];
    const int blk = blockIdx.x;              // (b*8+h)*20 + upair
    const int bh = blk / (UTOP/2), upair = blk % (UTOP/2);
    const int b = bh >> 3, h = bh & 7;
    const int u0 = upair * 2, u1 = u0 + 1;
    const int tid = threadIdx.x;
    if (tid < DHEAD) {
        const int l0 = Mtop[bh*UTOP + u0];
        const int l1 = Mtop[bh*UTOP + u1];
        qsel0[tid] = q[(size_t)(b*NUM_NODES + l0)*HID + h*DHEAD + tid];
        qsel1[tid] = q[(size_t)(b*NUM_NODES + l1)*HID + h*DHEAD + tid];
    }
    __syncthreads();
    const float scale = 0.17677669529663687f; // 1/sqrt(32)
    float lmax0 = -INFINITY, lmax1 = -INFINITY;
    for (int j = tid; j < NUM_NODES; j += 256) {
        const float4* kp = (const float4*)(k + (size_t)(b*NUM_NODES + j)*HID + h*DHEAD);
        const float4* q0 = (const float4*)qsel0;
        const float4* q1 = (const float4*)qsel1;
        float a0 = 0.f, a1 = 0.f;
        #pragma unroll
        for (int d4 = 0; d4 < 8; ++d4) {
            float4 kv = kp[d4];
            float4 v0 = q0[d4], v1 = q1[d4];
            a0 += v0.x*kv.x + v0.y*kv.y + v0.z*kv.z + v0.w*kv.w;
            a1 += v1.x*kv.x + v1.y*kv.y + v1.z*kv.z + v1.w*kv.w;
        }
        a0 *= scale; a1 *= scale;
        sc0[j] = a0; sc1[j] = a1;
        lmax0 = fmaxf(lmax0, a0);
        lmax1 = fmaxf(lmax1, a1);
    }
    #pragma unroll
    for (int m = 32; m >= 1; m >>= 1) {
        lmax0 = fmaxf(lmax0, __shfl_xor(lmax0, m));
        lmax1 = fmaxf(lmax1, __shfl_xor(lmax1, m));
    }
    if ((tid & 63) == 0) { red[tid >> 6] = lmax0; red[4 + (tid >> 6)] = lmax1; }
    __syncthreads();
    const float gmax0 = fmaxf(fmaxf(red[0], red[1]), fmaxf(red[2], red[3]));
    const float gmax1 = fmaxf(fmaxf(red[4], red[5]), fmaxf(red[6], red[7]));
    float lsum0 = 0.f, lsum1 = 0.f;
    for (int j = tid; j < NUM_NODES; j += 256) {
        float e0 = expf(sc0[j] - gmax0);
        float e1 = expf(sc1[j] - gmax1);
        sc0[j] = e0; sc1[j] = e1;
        lsum0 += e0; lsum1 += e1;
    }
    #pragma unroll
    for (int m = 32; m >= 1; m >>= 1) {
        lsum0 += __shfl_xor(lsum0, m);
        lsum1 += __shfl_xor(lsum1, m);
    }
    if ((tid & 63) == 0) { red[8 + (tid >> 6)] = lsum0; red[12 + (tid >> 6)] = lsum1; }
    __syncthreads();
    const float rinv0 = 1.0f / (red[8] + red[9] + red[10] + red[11]);
    const float rinv1 = 1.0f / (red[12] + red[13] + red[14] + red[15]);
    const float thr = 1.0f / (float)NUM_NODES;
    float* a0p = attn + (size_t)(bh*UTOP + u0)*NUM_NODES;
    float* a1p = attn + (size_t)(bh*UTOP + u1)*NUM_NODES;
    for (int j4 = tid; j4 < NUM_NODES/4; j4 += 256) {
        float4 v0, v1;
        v0.x = sc0[j4*4+0]*rinv0; if (v0.x < thr) v0.x = 0.f;
        v0.y = sc0[j4*4+1]*rinv0; if (v0.y < thr) v0.y = 0.f;
        v0.z = sc0[j4*4+2]*rinv0; if (v0.z < thr) v0.z = 0.f;
        v0.w = sc0[j4*4+3]*rinv0; if (v0.w < thr) v0.w = 0.f;
        v1.x = sc1[j4*4+0]*rinv1; if (v1.x < thr) v1.x = 0.f;
        v1.y = sc1[j4*4+1]*rinv1; if (v1.y < thr) v1.y = 0.f;
        v1.z = sc1[j4*4+2]*rinv1; if (v1.z < thr) v1.z = 0.f;
        v1.w = sc1[j4*4+3]*rinv1; if (v1.w < thr) v1.w = 0.f;
        *(float4*)(a0p + j4*4) = v0;
        *(float4*)(a1p + j4*4) = v1;
    }
}

// ---------------- Kernel 6: combine heads -> output (scans Mtop directly) ----------------
__global__ __launch_bounds__(256) void combine_kernel(
    const float* __restrict__ attn, const int* __restrict__ Mtop,
    float* __restrict__ out)
{
    __shared__ int mtops[NHEAD*UTOP];
    __shared__ int us[NHEAD];
    const int bl = blockIdx.x;  // b*2048+l
    const int b = bl >> 11, l = bl & (NUM_NODES-1);
    const int tid = threadIdx.x;
    if (tid < NHEAD) us[tid] = -1;
    for (int i = tid; i < NHEAD*UTOP; i += 256) mtops[i] = Mtop[b*NHEAD*UTOP + i];
    __syncthreads();
    for (int i = tid; i < NHEAD*UTOP; i += 256) {
        if (mtops[i] == l) us[i / UTOP] = i % UTOP;
    }
    __syncthreads();
    const size_t outbase = (size_t)bl * NUM_NODES;
    for (int j4 = tid; j4 < NUM_NODES/4; j4 += 256) {
        float4 s = make_float4(0.f, 0.f, 0.f, 0.f);
        #pragma unroll
        for (int h = 0; h < NHEAD; ++h) {
            int u = us[h];
            if (u >= 0) {
                float4 a = *(const float4*)(attn + (size_t)((b*NHEAD + h)*UTOP + u)*NUM_NODES + j4*4);
                s.x += a.x; s.y += a.y; s.z += a.z; s.w += a.w;
            }
        }
        s.x *= 0.125f; s.y *= 0.125f; s.z *= 0.125f; s.w *= 0.125f;
        *(float4*)(out + outbase + j4*4) = s;
    }
}

extern "C" void kernel_launch(void* const* d_in, const int* in_sizes, int n_in,
                              void* d_out, int out_size, void* d_ws, size_t ws_size,
                              hipStream_t stream) {
    const float* x      = (const float*)d_in[0];
    const float* w0     = (const float*)d_in[1];
    const float* b0     = (const float*)d_in[2];
    const float* w1     = (const float*)d_in[3];
    const float* b1     = (const float*)d_in[4];
    const float* w2     = (const float*)d_in[5];
    const float* b2     = (const float*)d_in[6];
    const float* g0     = (const float*)d_in[7];
    const float* be0    = (const float*)d_in[8];
    const float* g1     = (const float*)d_in[9];
    const float* be1    = (const float*)d_in[10];
    const float* g2     = (const float*)d_in[11];
    const float* be2    = (const float*)d_in[12];
    const float* g3     = (const float*)d_in[13];
    const float* be3    = (const float*)d_in[14];
    const float* fc_w   = (const float*)d_in[15];
    const float* fc_b   = (const float*)d_in[16];
    const float* q_w    = (const float*)d_in[17];
    const float* q_b    = (const float*)d_in[18];
    const float* k_w    = (const float*)d_in[19];
    const float* k_b    = (const float*)d_in[20];
    const int* idx_g    = (const int*)d_in[21];
    float* out = (float*)d_out;

    float* Hflat   = (float*)d_ws;                       // 4096*608
    float* q_ws    = Hflat + (size_t)ROWS*FCIN;          // 4096*256
    float* k_ws    = q_ws + (size_t)ROWS*HID;            // 4096*256
    float* M_ws    = k_ws + (size_t)ROWS*HID;            // 2*8*2048
    float* attn_ws = M_ws + (size_t)BATCH*NHEAD*NUM_NODES;   // 2*8*40*2048
    int*   Mtop    = (int*)(attn_ws + (size_t)BATCH*NHEAD*UTOP*NUM_NODES); // 640
    float* fc_wT   = (float*)(Mtop + BATCH*NHEAD*UTOP);  // 608*256
    float* q_wT    = fc_wT + (size_t)FCIN*HID;           // 256*256
    float* k_wT    = q_wT + (size_t)HID*HID;             // 256*256

    {
        dim3 tgrid((FCIN + 31)/32, (HID + 31)/32, 3);
        transpose3_kernel<<<tgrid, 256, 0, stream>>>(fc_w, q_w, k_w, fc_wT, q_wT, k_wT);
    }
    conv_chain_kernel<<<ROWS/4, 256, 0, stream>>>(x, w0, b0, w1, b1, w2, b2,
                                                  g0, be0, g1, be1, g2, be2, Hflat);
    fc_qk_kernel<<<ROWS/16, 512, 0, stream>>>(Hflat, fc_wT, fc_b, g3, be3,
                                              q_wT, q_b, k_wT, k_b, q_ws, k_ws);
    qk_sample_kernel<<<BATCH*NUM_NODES, 256, 0, stream>>>(q_ws, k_ws, idx_g, M_ws);
    topk_kernel<<<BATCH*NHEAD, 256, 0, stream>>>(M_ws, Mtop);
    attn_kernel<<<BATCH*NHEAD*UTOP/2, 256, 0, stream>>>(q_ws, k_ws, Mtop, attn_ws);
    combine_kernel<<<BATCH*NUM_NODES, 256, 0, stream>>>(attn_ws, Mtop, out);
}